// Round 2
// baseline (845.480 us; speedup 1.0000x reference)
//
#include <hip/hip_runtime.h>
#include <math.h>

#define B_ 16
#define H_ 256
#define L_ 4096
#define N_ 64
#define HN (H_*N_)
#define HL (H_*L_)
#define BHL (B_*H_*L_)

// ---------------------------------------------------------------------------
// Kernel 1: per-(h,dir,n) params, interleaved float4 {w_re, w_im, c2_re, c2_im}
// c2 = 2 * C * (exp(dtA)-1)/A
// ---------------------------------------------------------------------------
__global__ void params_kernel(const float* __restrict__ log_dt,
                              const float* __restrict__ A_re,
                              const float* __restrict__ A_im,
                              const float* __restrict__ C_re,
                              const float* __restrict__ C_im,
                              float4* __restrict__ P2) {
    int i = blockIdx.x * blockDim.x + threadIdx.x;  // i = h*64 + n
    if (i >= HN) return;
    int h = i >> 6, n = i & 63;
    float dt  = expf(log_dt[h]);
    float Are = A_re[i], Aim = A_im[i];
    float dr = dt * Are, di = dt * Aim;
    float er = expf(dr);
    float wr = er * cosf(di);
    float wi = er * sinf(di);
    float em1r = wr - 1.0f, em1i = wi;
    float inv = 1.0f / (Are*Are + Aim*Aim);
    float qr = (em1r*Are + em1i*Aim) * inv;
    float qi = (em1i*Are - em1r*Aim) * inv;
    #pragma unroll
    for (int d = 0; d < 2; ++d) {
        float Cr = C_re[d*HN + i], Ci = C_im[d*HN + i];
        float4 p;
        p.x = wr; p.y = wi;
        p.z = 2.0f*(Cr*qr - Ci*qi);
        p.w = 2.0f*(Cr*qi + Ci*qr);
        P2[(h*2 + d)*64 + n] = p;
    }
}

// ---------------------------------------------------------------------------
// Kernel 2: LayerNorm over channel dim H for each (b,l).
// ---------------------------------------------------------------------------
__global__ void __launch_bounds__(256) ln_kernel(const float* __restrict__ x,
                                                 const float* __restrict__ lnw,
                                                 const float* __restrict__ lnb,
                                                 float* __restrict__ z) {
    int b  = blockIdx.y;
    int l0 = blockIdx.x * 256;
    int t  = threadIdx.x;
    int hq = t >> 6, lo = t & 63;
    int l  = l0 + lo * 4;
    __shared__ float4 r1[4][64];
    __shared__ float4 r2[4][64];
    __shared__ float4 muS[64];
    __shared__ float4 rsS[64];
    const float* xb = x + (size_t)b * HL;
    float4 s1 = {0.f,0.f,0.f,0.f}, s2 = {0.f,0.f,0.f,0.f};
    #pragma unroll 4
    for (int hh = 0; hh < 64; ++hh) {
        int h = hq * 64 + hh;
        float4 v = *(const float4*)(xb + (size_t)h * L_ + l);
        s1.x += v.x; s1.y += v.y; s1.z += v.z; s1.w += v.w;
        s2.x += v.x*v.x; s2.y += v.y*v.y; s2.z += v.z*v.z; s2.w += v.w*v.w;
    }
    r1[hq][lo] = s1; r2[hq][lo] = s2;
    __syncthreads();
    if (t < 64) {
        float4 S1 = r1[0][t], S2 = r2[0][t];
        #pragma unroll
        for (int q = 1; q < 4; ++q) {
            float4 a = r1[q][t], c = r2[q][t];
            S1.x += a.x; S1.y += a.y; S1.z += a.z; S1.w += a.w;
            S2.x += c.x; S2.y += c.y; S2.z += c.z; S2.w += c.w;
        }
        const float invH = 1.0f / 256.0f;
        float4 mu, rs;
        mu.x = S1.x*invH; mu.y = S1.y*invH; mu.z = S1.z*invH; mu.w = S1.w*invH;
        rs.x = rsqrtf(S2.x*invH - mu.x*mu.x + 1e-5f);
        rs.y = rsqrtf(S2.y*invH - mu.y*mu.y + 1e-5f);
        rs.z = rsqrtf(S2.z*invH - mu.z*mu.z + 1e-5f);
        rs.w = rsqrtf(S2.w*invH - mu.w*mu.w + 1e-5f);
        muS[t] = mu; rsS[t] = rs;
    }
    __syncthreads();
    float4 mu = muS[lo], rs = rsS[lo];
    #pragma unroll 4
    for (int hh = 0; hh < 64; ++hh) {
        int h = hq * 64 + hh;
        float w = lnw[h], bb = lnb[h];
        float4 v = *(const float4*)(xb + (size_t)h * L_ + l);
        float4 zz;
        zz.x = (v.x - mu.x) * rs.x * w + bb;
        zz.y = (v.y - mu.y) * rs.y * w + bb;
        zz.z = (v.z - mu.z) * rs.z * w + bb;
        zz.w = (v.w - mu.w) * rs.w * w + bb;
        *(float4*)(z + (size_t)b * HL + (size_t)h * L_ + l) = zz;
    }
}

// ---------------------------------------------------------------------------
// Kernel 3: two-phase bidirectional S4D recurrence + fused epilogue.
// Block = (b,h), 128 threads = wave0 (fwd) + wave1 (bwd).
// Phase 1: lane = mode. Full scan, store packed-bf16 boundary states every 64
//          steps into LDS (swizzled col = (c+m)&63 -> conflict-free).
// Phase 2: lane = chunk (64 chunks of 64). Per mode: re-run recurrence from
//          boundary state, accumulate y[64] in registers. No LDS inner loop.
// Epilogue: bwd wave passes y via LDS; fwd wave adds D*z, GELU, writes g.
// ---------------------------------------------------------------------------
__device__ __forceinline__ unsigned int pk_bf2(float a, float b) {
    unsigned int ua = (__float_as_uint(a) + 0x8000u) & 0xffff0000u;
    unsigned int ub = (__float_as_uint(b) + 0x8000u) >> 16;
    return ua | ub;
}

#define FSTEP(zc)                                                          \
    {                                                                      \
        float nr_ = fmaf(wr, sr, fmaf(-wi, si, (zc)));                     \
        float ni_ = fmaf(wr, si, wi * sr);                                 \
        sr = nr_; si = ni_;                                                \
    }

__global__ void __launch_bounds__(128, 2) ssm_kernel(const float* __restrict__ z,
                                                     const float4* __restrict__ P2,
                                                     const float* __restrict__ D,
                                                     float* __restrict__ g) {
    int bh = blockIdx.x;
    int h  = bh & (H_ - 1);
    int t  = threadIdx.x;
    int lane = t & 63;
    int dir  = t >> 6;
    const float*  zr = z + (size_t)bh * L_;
    const float4* zq = (const float4*)zr;
    __shared__ unsigned int smem[2 * 64 * 64];   // 32 KB

    // ---------------- phase 1: boundary-state scan (lane = mode) ----------
    {
        int m = lane;
        float4 wp = P2[(h * 2 + dir) * 64 + m];
        float wr = wp.x, wi = wp.y;
        float sr = 0.f, si = 0.f;
        unsigned int* strow = smem + (dir * 64 + m) * 64;
        if (dir == 0) {
            strow[m & 63] = 0u;  // B_f(0) = 0
            for (int cc = 0; cc < 64; ++cc) {
                #pragma unroll
                for (int q = 0; q < 16; ++q) {
                    float4 zv = zq[cc * 16 + q];
                    FSTEP(zv.x); FSTEP(zv.y); FSTEP(zv.z); FSTEP(zv.w);
                }
                if (cc != 63) strow[((cc + 1) + m) & 63] = pk_bf2(sr, si);
            }
        } else {
            for (int cc = 63; cc >= 0; --cc) {
                strow[(cc + m) & 63] = pk_bf2(sr, si);  // state entering chunk cc from right
                #pragma unroll
                for (int q = 15; q >= 0; --q) {
                    float4 zv = zq[cc * 16 + q];
                    FSTEP(zv.w); FSTEP(zv.z); FSTEP(zv.y); FSTEP(zv.x);
                }
            }
        }
    }
    __syncthreads();

    // ---------------- phase 2: per-chunk output (lane = chunk) -------------
    int c = lane;
    float zreg[64], y[64];
    const float4* zc4 = (const float4*)(zr + c * 64);
    #pragma unroll
    for (int q = 0; q < 16; ++q) {
        float4 v = zc4[q];
        zreg[4*q+0] = v.x; zreg[4*q+1] = v.y; zreg[4*q+2] = v.z; zreg[4*q+3] = v.w;
    }
    #pragma unroll
    for (int j = 0; j < 64; ++j) y[j] = 0.f;

    const float4* Ph = P2 + (h * 2 + dir) * 64;
    const unsigned int* stbase = smem + dir * 64 * 64;
    for (int m = 0; m < 64; ++m) {
        float4 wp = Ph[m];
        float wr = wp.x, wi = wp.y, cr = wp.z, ci = wp.w;
        unsigned int pk = stbase[m * 64 + ((c + m) & 63)];
        float sr = __uint_as_float(pk & 0xffff0000u);
        float si = __uint_as_float(pk << 16);
        if (dir == 0) {
            #pragma unroll
            for (int j = 0; j < 64; ++j) {
                FSTEP(zreg[j]);
                y[j] = fmaf(cr, sr, y[j]);
                y[j] = fmaf(-ci, si, y[j]);
            }
        } else {
            #pragma unroll
            for (int j = 63; j >= 0; --j) {
                y[j] = fmaf(cr, sr, y[j]);
                y[j] = fmaf(-ci, si, y[j]);
                FSTEP(zreg[j]);
            }
        }
    }
    __syncthreads();

    // ---------------- epilogue: combine + GELU + store g -------------------
    float* yl = (float*)smem;            // reuse: 64 rows x 68 floats = 17.4 KB
    if (dir == 1) {
        #pragma unroll
        for (int q = 0; q < 16; ++q) {
            float4 v;
            v.x = y[4*q+0]; v.y = y[4*q+1]; v.z = y[4*q+2]; v.w = y[4*q+3];
            *(float4*)&yl[c * 68 + 4 * q] = v;
        }
    }
    __syncthreads();
    if (dir == 0) {
        float dh = D[h];
        float* go = g + (size_t)bh * L_ + c * 64;
        #pragma unroll
        for (int q = 0; q < 16; ++q) {
            float4 yb = *(const float4*)&yl[c * 68 + 4 * q];
            float u0 = y[4*q+0] + yb.x + dh * zreg[4*q+0];
            float u1 = y[4*q+1] + yb.y + dh * zreg[4*q+1];
            float u2 = y[4*q+2] + yb.z + dh * zreg[4*q+2];
            float u3 = y[4*q+3] + yb.w + dh * zreg[4*q+3];
            float4 o;
            o.x = 0.5f*u0*(1.0f + tanhf(0.7978845608028654f*(u0 + 0.044715f*u0*u0*u0)));
            o.y = 0.5f*u1*(1.0f + tanhf(0.7978845608028654f*(u1 + 0.044715f*u1*u1*u1)));
            o.z = 0.5f*u2*(1.0f + tanhf(0.7978845608028654f*(u2 + 0.044715f*u2*u2*u2)));
            o.w = 0.5f*u3*(1.0f + tanhf(0.7978845608028654f*(u3 + 0.044715f*u3*u3*u3)));
            *(float4*)go = o;
            go += 4;
        }
    }
}

// ---------------------------------------------------------------------------
// Kernel 4: out[b,o,l] = x[b,o,l] + b_out[o] + sum_h W[o,h]*g[b,h,l]
// ---------------------------------------------------------------------------
__global__ void __launch_bounds__(256) outproj_kernel(const float* __restrict__ g,
                                                      const float* __restrict__ x,
                                                      const float* __restrict__ W,
                                                      const float* __restrict__ bias,
                                                      float* __restrict__ out) {
    int b  = blockIdx.z;
    int o0 = blockIdx.y * 64;
    int l0 = blockIdx.x * 64;
    int t  = threadIdx.x;
    __shared__ float Ws[16][68];
    __shared__ float Gs[16][64];
    float acc[4][4];
    #pragma unroll
    for (int i = 0; i < 4; ++i)
        #pragma unroll
        for (int j = 0; j < 4; ++j) acc[i][j] = 0.f;
    int to = (t >> 4) << 2;
    int tl = (t & 15) << 2;
    int wrow = t >> 2;
    int wcg  = (t & 3) << 2;
    int grow = t >> 4;
    for (int h0 = 0; h0 < H_; h0 += 16) {
        float4 wv = *(const float4*)(W + (size_t)(o0 + wrow) * H_ + h0 + wcg);
        float4 gv = *(const float4*)(g + ((size_t)(b * H_ + h0 + grow)) * L_ + l0 + tl);
        __syncthreads();
        Ws[wcg + 0][wrow] = wv.x;
        Ws[wcg + 1][wrow] = wv.y;
        Ws[wcg + 2][wrow] = wv.z;
        Ws[wcg + 3][wrow] = wv.w;
        *(float4*)&Gs[grow][tl] = gv;
        __syncthreads();
        #pragma unroll
        for (int kk = 0; kk < 16; ++kk) {
            float4 a4 = *(const float4*)&Ws[kk][to];
            float4 b4 = *(const float4*)&Gs[kk][tl];
            float av[4] = {a4.x, a4.y, a4.z, a4.w};
            float bv[4] = {b4.x, b4.y, b4.z, b4.w};
            #pragma unroll
            for (int ii = 0; ii < 4; ++ii)
                #pragma unroll
                for (int ji = 0; ji < 4; ++ji)
                    acc[ii][ji] = fmaf(av[ii], bv[ji], acc[ii][ji]);
        }
    }
    #pragma unroll
    for (int ii = 0; ii < 4; ++ii) {
        int o = o0 + to + ii;
        float bo = bias[o];
        size_t off = ((size_t)(b * H_ + o)) * L_ + l0 + tl;
        float4 xr = *(const float4*)(x + off);
        float4 ov;
        ov.x = xr.x + bo + acc[ii][0];
        ov.y = xr.y + bo + acc[ii][1];
        ov.z = xr.z + bo + acc[ii][2];
        ov.w = xr.w + bo + acc[ii][3];
        *(float4*)(out + off) = ov;
    }
}

// ---------------------------------------------------------------------------
extern "C" void kernel_launch(void* const* d_in, const int* in_sizes, int n_in,
                              void* d_out, int out_size, void* d_ws, size_t ws_size,
                              hipStream_t stream) {
    const float* x      = (const float*)d_in[0];
    const float* log_dt = (const float*)d_in[1];
    const float* A_re   = (const float*)d_in[2];
    const float* A_im   = (const float*)d_in[3];
    const float* C_re   = (const float*)d_in[4];
    const float* C_im   = (const float*)d_in[5];
    const float* D      = (const float*)d_in[6];
    const float* lnw    = (const float*)d_in[7];
    const float* lnb    = (const float*)d_in[8];
    const float* W      = (const float*)d_in[9];
    const float* bout   = (const float*)d_in[10];
    float* out = (float*)d_out;
    float* ws  = (float*)d_ws;

    float* z  = ws;                          // BHL
    float* g  = ws + (size_t)BHL;            // BHL
    float4* P2 = (float4*)(ws + 2*(size_t)BHL); // 2*HN float4

    params_kernel<<<(HN + 255) / 256, 256, 0, stream>>>(log_dt, A_re, A_im, C_re, C_im, P2);
    ln_kernel<<<dim3(L_ / 256, B_), 256, 0, stream>>>(x, lnw, lnb, z);
    ssm_kernel<<<B_ * H_, 128, 0, stream>>>(z, P2, D, g);
    outproj_kernel<<<dim3(L_ / 64, H_ / 64, B_), 256, 0, stream>>>(g, x, W, bout, out);
}

// Round 3
// 287.227 us; speedup vs baseline: 2.9436x; 2.9436x over previous
//
#include <hip/hip_runtime.h>
#include <math.h>

#define B_ 16
#define H_ 256
#define L_ 4096
#define N_ 64
#define HN (H_*N_)
#define HL (H_*L_)
#define BHL (B_*H_*L_)

// per-(h,dir) precomputed bf16 matrices, 20480 elems each:
//   WvT  [128][64]  at +0      : WvT[2m+ri][i] = (re,im) of w^(dir0: 63-i, dir1: i)
//   Tm   [64][64]   at +8192   : Tm[j][i] = dir0: (i<=j ? K[j-i] : 0), dir1: (i>j ? K[i-j-1] : 0)
//   E2T  [64][128]  at +12288  : E2T[j][2m]=Re(c2*w^p), [2m+1]=-Im(c2*w^p), p = dir0: j+1, dir1: 63-j
#define WVT_OFS 0
#define TM_OFS  8192
#define E2T_OFS 12288
#define MATS_PER 20480

typedef short bf16x8 __attribute__((ext_vector_type(8)));
typedef float f32x4  __attribute__((ext_vector_type(4)));

__device__ __forceinline__ unsigned int pk2(float a, float b) {
    // a -> low 16 (lower address), b -> high 16
    return ((__float_as_uint(a) + 0x8000u) >> 16) |
           ((__float_as_uint(b) + 0x8000u) & 0xffff0000u);
}
__device__ __forceinline__ unsigned short bfr(float a) {
    return (unsigned short)((__float_as_uint(a) + 0x8000u) >> 16);
}
__device__ __forceinline__ float ubf(unsigned short u) {
    return __uint_as_float(((unsigned int)u) << 16);
}

// ---------------------------------------------------------------------------
// Kernel 1: build per-(h,dir) matrices + w^64. 1 wave per (h,dir).
// ---------------------------------------------------------------------------
__global__ void __launch_bounds__(64) mats_kernel(const float* __restrict__ log_dt,
                                                  const float* __restrict__ A_re,
                                                  const float* __restrict__ A_im,
                                                  const float* __restrict__ C_re,
                                                  const float* __restrict__ C_im,
                                                  unsigned short* __restrict__ mats,
                                                  float2* __restrict__ Wc) {
    int hd = blockIdx.x;
    int h = hd >> 1, d = hd & 1;
    int m = threadIdx.x;
    __shared__ float2 pws[65 * 64];   // pws[k][(m+k)&63] = w_m^k  (swizzled)
    __shared__ float2 c2s[64];
    __shared__ float  Karr[64];

    int i = h * 64 + m;
    float dt = expf(log_dt[h]);
    float Are = A_re[i], Aim = A_im[i];
    float dr = dt * Are, di = dt * Aim;
    float er = expf(dr);
    float wr = er * cosf(di), wi = er * sinf(di);
    float em1r = wr - 1.0f, em1i = wi;
    float inv = 1.0f / (Are * Are + Aim * Aim);
    float qr = (em1r * Are + em1i * Aim) * inv;
    float qi = (em1i * Are - em1r * Aim) * inv;
    float Cr = C_re[d * HN + i], Ci = C_im[d * HN + i];
    float2 c2;
    c2.x = 2.0f * (Cr * qr - Ci * qi);
    c2.y = 2.0f * (Cr * qi + Ci * qr);
    c2s[m] = c2;
    float pr = 1.0f, pi = 0.0f;
    for (int k = 0; k < 64; ++k) {
        float2 p; p.x = pr; p.y = pi;
        pws[k * 64 + ((m + k) & 63)] = p;
        float t = pr * wr - pi * wi;
        pi = pr * wi + pi * wr;
        pr = t;
    }
    {   // k = 64
        float2 p; p.x = pr; p.y = pi;
        pws[64 * 64 + ((m + 64) & 63)] = p;
        Wc[hd * 64 + m] = p;
    }
    __syncthreads();
    // K[m] = sum_mm Re(c2[mm] * w_mm^m)
    {
        float kk = 0.f;
        for (int mm = 0; mm < 64; ++mm) {
            float2 c = c2s[mm];
            float2 pw = pws[m * 64 + ((mm + m) & 63)];
            kk += c.x * pw.x - c.y * pw.y;
        }
        Karr[m] = kk;
    }
    __syncthreads();
    unsigned short* mb = mats + (size_t)hd * MATS_PER;
    // WvT rows 2m, 2m+1
    for (int i2 = 0; i2 < 32; ++i2) {
        int e0 = 2 * i2, e1 = e0 + 1;
        int k0 = d ? e0 : 63 - e0;
        int k1 = d ? e1 : 63 - e1;
        float2 p0 = pws[k0 * 64 + ((m + k0) & 63)];
        float2 p1 = pws[k1 * 64 + ((m + k1) & 63)];
        *(unsigned int*)(mb + WVT_OFS + (2 * m) * 64 + e0)     = pk2(p0.x, p1.x);
        *(unsigned int*)(mb + WVT_OFS + (2 * m + 1) * 64 + e0) = pk2(p0.y, p1.y);
    }
    // Tm row j = m
    for (int i2 = 0; i2 < 32; ++i2) {
        int e0 = 2 * i2, e1 = e0 + 1;
        float v0, v1;
        if (d == 0) {
            v0 = (e0 <= m) ? Karr[m - e0] : 0.f;
            v1 = (e1 <= m) ? Karr[m - e1] : 0.f;
        } else {
            v0 = (e0 > m) ? Karr[e0 - m - 1] : 0.f;
            v1 = (e1 > m) ? Karr[e1 - m - 1] : 0.f;
        }
        *(unsigned int*)(mb + TM_OFS + m * 64 + e0) = pk2(v0, v1);
    }
    // E2T row j = m
    {
        int kp = d ? (63 - m) : (m + 1);
        for (int mm = 0; mm < 64; ++mm) {
            float2 c = c2s[mm];
            float2 pw = pws[kp * 64 + ((mm + kp) & 63)];
            float vr = c.x * pw.x - c.y * pw.y;
            float vi = -(c.x * pw.y + c.y * pw.x);
            *(unsigned int*)(mb + E2T_OFS + m * 128 + 2 * mm) = pk2(vr, vi);
        }
    }
}

// ---------------------------------------------------------------------------
// Kernel 2: LayerNorm over channel dim H for each (b,l).
// ---------------------------------------------------------------------------
__global__ void __launch_bounds__(256) ln_kernel(const float* __restrict__ x,
                                                 const float* __restrict__ lnw,
                                                 const float* __restrict__ lnb,
                                                 float* __restrict__ z) {
    int b  = blockIdx.y;
    int l0 = blockIdx.x * 256;
    int t  = threadIdx.x;
    int hq = t >> 6, lo = t & 63;
    int l  = l0 + lo * 4;
    __shared__ float4 r1[4][64];
    __shared__ float4 r2[4][64];
    __shared__ float4 muS[64];
    __shared__ float4 rsS[64];
    const float* xb = x + (size_t)b * HL;
    float4 s1 = {0.f,0.f,0.f,0.f}, s2 = {0.f,0.f,0.f,0.f};
    #pragma unroll 4
    for (int hh = 0; hh < 64; ++hh) {
        int h = hq * 64 + hh;
        float4 v = *(const float4*)(xb + (size_t)h * L_ + l);
        s1.x += v.x; s1.y += v.y; s1.z += v.z; s1.w += v.w;
        s2.x += v.x*v.x; s2.y += v.y*v.y; s2.z += v.z*v.z; s2.w += v.w*v.w;
    }
    r1[hq][lo] = s1; r2[hq][lo] = s2;
    __syncthreads();
    if (t < 64) {
        float4 S1 = r1[0][t], S2 = r2[0][t];
        #pragma unroll
        for (int q = 1; q < 4; ++q) {
            float4 a = r1[q][t], c = r2[q][t];
            S1.x += a.x; S1.y += a.y; S1.z += a.z; S1.w += a.w;
            S2.x += c.x; S2.y += c.y; S2.z += c.z; S2.w += c.w;
        }
        const float invH = 1.0f / 256.0f;
        float4 mu, rs;
        mu.x = S1.x*invH; mu.y = S1.y*invH; mu.z = S1.z*invH; mu.w = S1.w*invH;
        rs.x = rsqrtf(S2.x*invH - mu.x*mu.x + 1e-5f);
        rs.y = rsqrtf(S2.y*invH - mu.y*mu.y + 1e-5f);
        rs.z = rsqrtf(S2.z*invH - mu.z*mu.z + 1e-5f);
        rs.w = rsqrtf(S2.w*invH - mu.w*mu.w + 1e-5f);
        muS[t] = mu; rsS[t] = rs;
    }
    __syncthreads();
    float4 mu = muS[lo], rs = rsS[lo];
    #pragma unroll 4
    for (int hh = 0; hh < 64; ++hh) {
        int h = hq * 64 + hh;
        float w = lnw[h], bb = lnb[h];
        float4 v = *(const float4*)(xb + (size_t)h * L_ + l);
        float4 zz;
        zz.x = (v.x - mu.x) * rs.x * w + bb;
        zz.y = (v.y - mu.y) * rs.y * w + bb;
        zz.z = (v.z - mu.z) * rs.z * w + bb;
        zz.w = (v.w - mu.w) * rs.w * w + bb;
        *(float4*)(z + (size_t)b * HL + (size_t)h * L_ + l) = zz;
    }
}

// ---------------------------------------------------------------------------
// Kernel 3: MFMA chunked S4D. Block = (b,h), 256 threads = 4 waves:
// wave = dir*2 + p.  Chunks of 64: U=Z*Wv (MFMA) -> 64-step scan -> Y = Z*T^T
// + Sb*E2^T (MFMA, acc-chained) -> exchange dirs via LDS -> D*z + GELU -> g.
// ---------------------------------------------------------------------------
#define MFMA16(a,b,c) __builtin_amdgcn_mfma_f32_16x16x32_bf16((a),(b),(c),0,0,0)

__global__ void __launch_bounds__(256, 2) ssm_kernel(const float* __restrict__ z,
                                                     const unsigned short* __restrict__ mats,
                                                     const float2* __restrict__ Wc,
                                                     const float* __restrict__ D,
                                                     float* __restrict__ g) {
    int bh = blockIdx.x;
    int h  = bh & (H_ - 1);
    int t  = threadIdx.x;
    int w  = t >> 6, l = t & 63;
    int d  = w >> 1, p = w & 1;

    __shared__ unsigned int sZb[64 * 32];      // [c][i] bf16, 8 KB, swizzled
    __shared__ unsigned int sU[2][64 * 64];    // [c][2m|2m+1] bf16 -> Sb2 -> Ybuf

    const unsigned short* mb = mats + (size_t)(h * 2 + d) * MATS_PER;

    // ---- stage Z -> bf16 LDS (swizzled byte ^= (row&7)<<4) ----
    {
        int r = t >> 2, q = t & 3;
        const float* zp = z + (size_t)bh * L_ + r * 64 + q * 16;
        float4 v0 = *(const float4*)(zp + 0);
        float4 v1 = *(const float4*)(zp + 4);
        float4 v2 = *(const float4*)(zp + 8);
        float4 v3 = *(const float4*)(zp + 12);
        uint4 u0, u1;
        u0.x = pk2(v0.x, v0.y); u0.y = pk2(v0.z, v0.w);
        u0.z = pk2(v1.x, v1.y); u0.w = pk2(v1.z, v1.w);
        u1.x = pk2(v2.x, v2.y); u1.y = pk2(v2.z, v2.w);
        u1.z = pk2(v3.x, v3.y); u1.w = pk2(v3.z, v3.w);
        unsigned int base = r * 128 + q * 32;
        unsigned int sw = (r & 7) << 4;
        *(uint4*)((char*)sZb + ((base) ^ sw))      = u0;
        *(uint4*)((char*)sZb + ((base + 16) ^ sw)) = u1;
    }
    __syncthreads();

    // ---- load Z A-frags (shared by M1 and M2) ----
    bf16x8 za[4][2];
    int arow = l & 15;
    int koff = (l >> 4) * 8;
    #pragma unroll
    for (int cb = 0; cb < 4; ++cb) {
        int row = cb * 16 + arow;
        unsigned int sw = (row & 7) << 4;
        #pragma unroll
        for (int kb = 0; kb < 2; ++kb) {
            unsigned int byte = (row * 128 + (kb * 32 + koff) * 2) ^ sw;
            za[cb][kb] = *(bf16x8*)((char*)sZb + byte);
        }
    }

    int urow = (l >> 4) * 2;  // (lane>>4)*4/2... row base = (l>>4)*4
    // ---- M1: U = Z * Wv ----
    #pragma unroll
    for (int mcb = 0; mcb < 4; ++mcb) {
        int mcblk = p * 4 + mcb;
        const unsigned short* wv = mb + WVT_OFS + (mcblk * 16 + arow) * 64 + koff;
        bf16x8 b0 = *(const bf16x8*)(wv);
        bf16x8 b1 = *(const bf16x8*)(wv + 32);
        #pragma unroll
        for (int cb = 0; cb < 4; ++cb) {
            f32x4 acc = {0.f, 0.f, 0.f, 0.f};
            acc = MFMA16(za[cb][0], b0, acc);
            acc = MFMA16(za[cb][1], b1, acc);
            int mc = mcblk * 16 + arow;
            #pragma unroll
            for (int rr = 0; rr < 4; ++rr) {
                int c = cb * 16 + (l >> 4) * 4 + rr;
                unsigned int byte = ((unsigned)(c * 256 + mc * 2)) ^ ((c & 7) << 4);
                *(unsigned short*)((char*)&sU[d][0] + byte) = bfr(acc[rr]);
            }
        }
    }
    __syncthreads();

    // ---- scan over 64 chunks (waves with p==0; lane = mode) ----
    if (p == 0) {
        float2 w64 = Wc[(h * 2 + d) * 64 + l];
        float sr = 0.f, si = 0.f;
        if (d == 0) {
            for (int c = 0; c < 64; ++c) {
                unsigned int byte = ((unsigned)(c * 256 + l * 4)) ^ ((c & 7) << 4);
                unsigned int uu = *(unsigned int*)((char*)&sU[0][0] + byte);
                float ur = __uint_as_float(uu << 16);
                float ui = __uint_as_float(uu & 0xffff0000u);
                *(unsigned int*)((char*)&sU[0][0] + byte) = pk2(sr, si);
                float nsr = fmaf(w64.x, sr, fmaf(-w64.y, si, ur));
                float nsi = fmaf(w64.x, si, fmaf(w64.y, sr, ui));
                sr = nsr; si = nsi;
            }
        } else {
            for (int c = 63; c >= 0; --c) {
                unsigned int byte = ((unsigned)(c * 256 + l * 4)) ^ ((c & 7) << 4);
                unsigned int uu = *(unsigned int*)((char*)&sU[1][0] + byte);
                float ur = __uint_as_float(uu << 16);
                float ui = __uint_as_float(uu & 0xffff0000u);
                *(unsigned int*)((char*)&sU[1][0] + byte) = pk2(sr, si);
                float nsr = fmaf(w64.x, sr, fmaf(-w64.y, si, ur));
                float nsi = fmaf(w64.x, si, fmaf(w64.y, sr, ui));
                sr = nsr; si = nsi;
            }
        }
    }
    __syncthreads();

    // ---- M2+M3: Y = Z*T^T + Sb*E2^T ----
    f32x4 yacc[2][4];
    #pragma unroll
    for (int jb = 0; jb < 2; ++jb) {
        int jblk = p * 2 + jb;
        const unsigned short* tm = mb + TM_OFS + (jblk * 16 + arow) * 64 + koff;
        bf16x8 tb0 = *(const bf16x8*)(tm);
        bf16x8 tb1 = *(const bf16x8*)(tm + 32);
        const unsigned short* et = mb + E2T_OFS + (jblk * 16 + arow) * 128 + koff;
        bf16x8 eb0 = *(const bf16x8*)(et);
        bf16x8 eb1 = *(const bf16x8*)(et + 32);
        bf16x8 eb2 = *(const bf16x8*)(et + 64);
        bf16x8 eb3 = *(const bf16x8*)(et + 96);
        #pragma unroll
        for (int cb = 0; cb < 4; ++cb) {
            f32x4 acc = {0.f, 0.f, 0.f, 0.f};
            acc = MFMA16(za[cb][0], tb0, acc);
            acc = MFMA16(za[cb][1], tb1, acc);
            int row = cb * 16 + arow;
            unsigned int sw = (row & 7) << 4;
            bf16x8 sa0 = *(bf16x8*)((char*)&sU[d][0] + (((unsigned)(row * 256 + (0 * 32 + koff) * 2)) ^ sw));
            bf16x8 sa1 = *(bf16x8*)((char*)&sU[d][0] + (((unsigned)(row * 256 + (1 * 32 + koff) * 2)) ^ sw));
            bf16x8 sa2 = *(bf16x8*)((char*)&sU[d][0] + (((unsigned)(row * 256 + (2 * 32 + koff) * 2)) ^ sw));
            bf16x8 sa3 = *(bf16x8*)((char*)&sU[d][0] + (((unsigned)(row * 256 + (3 * 32 + koff) * 2)) ^ sw));
            acc = MFMA16(sa0, eb0, acc);
            acc = MFMA16(sa1, eb1, acc);
            acc = MFMA16(sa2, eb2, acc);
            acc = MFMA16(sa3, eb3, acc);
            yacc[jb][cb] = acc;
        }
    }
    __syncthreads();

    // ---- exchange: dir1 writes Y_bwd; dir0 combines + GELU + store ----
    float* Yb = (float*)&sU[0][0];       // [c][j] stride 66, 16.9 KB (U dead)
    if (d == 1) {
        #pragma unroll
        for (int jb = 0; jb < 2; ++jb) {
            int j = (p * 2 + jb) * 16 + arow;
            #pragma unroll
            for (int cb = 0; cb < 4; ++cb) {
                #pragma unroll
                for (int rr = 0; rr < 4; ++rr) {
                    int c = cb * 16 + (l >> 4) * 4 + rr;
                    Yb[c * 66 + j] = yacc[jb][cb][rr];
                }
            }
        }
    }
    __syncthreads();
    if (d == 0) {
        float dv = D[h];
        float* go = g + (size_t)bh * L_;
        #pragma unroll
        for (int jb = 0; jb < 2; ++jb) {
            int j = (p * 2 + jb) * 16 + arow;
            #pragma unroll
            for (int cb = 0; cb < 4; ++cb) {
                #pragma unroll
                for (int rr = 0; rr < 4; ++rr) {
                    int c = cb * 16 + (l >> 4) * 4 + rr;
                    unsigned int zbyte = ((unsigned)(c * 128 + j * 2)) ^ ((c & 7) << 4);
                    float zv = ubf(*(unsigned short*)((char*)sZb + zbyte));
                    float y = yacc[jb][cb][rr] + Yb[c * 66 + j] + dv * zv;
                    float inner = 0.7978845608028654f * (y + 0.044715f * y * y * y);
                    go[c * 64 + j] = 0.5f * y * (1.0f + tanhf(inner));
                }
            }
        }
    }
}

// ---------------------------------------------------------------------------
// Kernel 4: out[b,o,l] = x[b,o,l] + b_out[o] + sum_h W[o,h]*g[b,h,l]
// ---------------------------------------------------------------------------
__global__ void __launch_bounds__(256) outproj_kernel(const float* __restrict__ g,
                                                      const float* __restrict__ x,
                                                      const float* __restrict__ W,
                                                      const float* __restrict__ bias,
                                                      float* __restrict__ out) {
    int b  = blockIdx.z;
    int o0 = blockIdx.y * 64;
    int l0 = blockIdx.x * 64;
    int t  = threadIdx.x;
    __shared__ float Ws[16][68];
    __shared__ float Gs[16][64];
    float acc[4][4];
    #pragma unroll
    for (int i = 0; i < 4; ++i)
        #pragma unroll
        for (int j = 0; j < 4; ++j) acc[i][j] = 0.f;
    int to = (t >> 4) << 2;
    int tl = (t & 15) << 2;
    int wrow = t >> 2;
    int wcg  = (t & 3) << 2;
    int grow = t >> 4;
    for (int h0 = 0; h0 < H_; h0 += 16) {
        float4 wv = *(const float4*)(W + (size_t)(o0 + wrow) * H_ + h0 + wcg);
        float4 gv = *(const float4*)(g + ((size_t)(b * H_ + h0 + grow)) * L_ + l0 + tl);
        __syncthreads();
        Ws[wcg + 0][wrow] = wv.x;
        Ws[wcg + 1][wrow] = wv.y;
        Ws[wcg + 2][wrow] = wv.z;
        Ws[wcg + 3][wrow] = wv.w;
        *(float4*)&Gs[grow][tl] = gv;
        __syncthreads();
        #pragma unroll
        for (int kk = 0; kk < 16; ++kk) {
            float4 a4 = *(const float4*)&Ws[kk][to];
            float4 b4 = *(const float4*)&Gs[kk][tl];
            float av[4] = {a4.x, a4.y, a4.z, a4.w};
            float bv[4] = {b4.x, b4.y, b4.z, b4.w};
            #pragma unroll
            for (int ii = 0; ii < 4; ++ii)
                #pragma unroll
                for (int ji = 0; ji < 4; ++ji)
                    acc[ii][ji] = fmaf(av[ii], bv[ji], acc[ii][ji]);
        }
    }
    #pragma unroll
    for (int ii = 0; ii < 4; ++ii) {
        int o = o0 + to + ii;
        float bo = bias[o];
        size_t off = ((size_t)(b * H_ + o)) * L_ + l0 + tl;
        float4 xr = *(const float4*)(x + off);
        float4 ov;
        ov.x = xr.x + bo + acc[ii][0];
        ov.y = xr.y + bo + acc[ii][1];
        ov.z = xr.z + bo + acc[ii][2];
        ov.w = xr.w + bo + acc[ii][3];
        *(float4*)(out + off) = ov;
    }
}

// ---------------------------------------------------------------------------
extern "C" void kernel_launch(void* const* d_in, const int* in_sizes, int n_in,
                              void* d_out, int out_size, void* d_ws, size_t ws_size,
                              hipStream_t stream) {
    const float* x      = (const float*)d_in[0];
    const float* log_dt = (const float*)d_in[1];
    const float* A_re   = (const float*)d_in[2];
    const float* A_im   = (const float*)d_in[3];
    const float* C_re   = (const float*)d_in[4];
    const float* C_im   = (const float*)d_in[5];
    const float* D      = (const float*)d_in[6];
    const float* lnw    = (const float*)d_in[7];
    const float* lnb    = (const float*)d_in[8];
    const float* W      = (const float*)d_in[9];
    const float* bout   = (const float*)d_in[10];
    float* out = (float*)d_out;
    float* ws  = (float*)d_ws;

    float* z = ws;                                   // BHL f32
    float* g = ws + (size_t)BHL;                     // BHL f32
    unsigned short* mats = (unsigned short*)(ws + 2 * (size_t)BHL);  // 512*20480 bf16
    float2* Wc = (float2*)(ws + 2 * (size_t)BHL + (512 * (size_t)MATS_PER) / 2);  // 512*64 cplx

    mats_kernel<<<512, 64, 0, stream>>>(log_dt, A_re, A_im, C_re, C_im, mats, Wc);
    ln_kernel<<<dim3(L_ / 256, B_), 256, 0, stream>>>(x, lnw, lnb, z);
    ssm_kernel<<<B_ * H_, 256, 0, stream>>>(z, mats, Wc, D, g);
    outproj_kernel<<<dim3(L_ / 64, H_ / 64, B_), 256, 0, stream>>>(g, x, W, bout, out);
}

// Round 4
// 228.352 us; speedup vs baseline: 3.7025x; 1.2578x over previous
//
#include <hip/hip_runtime.h>
#include <math.h>

#define B_ 16
#define H_ 256
#define L_ 4096
#define N_ 64
#define HN (H_*N_)
#define HL (H_*L_)
#define BHL (B_*H_*L_)

// per-(h,dir) precomputed bf16 matrices, 20480 elems each:
//   WvT  [128][64]  at +0      : WvT[2m+ri][i] = (re,im) of w^(dir0: 63-i, dir1: i)
//   Tm   [64][64]   at +8192   : Tm[j][i] = dir0: (i<=j ? K[j-i] : 0), dir1: (i>j ? K[i-j-1] : 0)
//   E2T  [64][128]  at +12288  : E2T[j][2m]=Re(c2*w^p), [2m+1]=-Im(c2*w^p), p = dir0: j+1, dir1: 63-j
#define WVT_OFS 0
#define TM_OFS  8192
#define E2T_OFS 12288
#define MATS_PER 20480

typedef short bf16x8 __attribute__((ext_vector_type(8)));
typedef float f32x4  __attribute__((ext_vector_type(4)));

__device__ __forceinline__ unsigned int pk2(float a, float b) {
    return ((__float_as_uint(a) + 0x8000u) >> 16) |
           ((__float_as_uint(b) + 0x8000u) & 0xffff0000u);
}
__device__ __forceinline__ unsigned short bfr(float a) {
    return (unsigned short)((__float_as_uint(a) + 0x8000u) >> 16);
}
__device__ __forceinline__ float ubf(unsigned short u) {
    return __uint_as_float(((unsigned int)u) << 16);
}

// ---------------------------------------------------------------------------
// Kernel 1: build per-(h,dir) matrices + w^64. 1 wave per (h,dir).
// ---------------------------------------------------------------------------
__global__ void __launch_bounds__(64) mats_kernel(const float* __restrict__ log_dt,
                                                  const float* __restrict__ A_re,
                                                  const float* __restrict__ A_im,
                                                  const float* __restrict__ C_re,
                                                  const float* __restrict__ C_im,
                                                  unsigned short* __restrict__ mats,
                                                  float2* __restrict__ Wc) {
    int hd = blockIdx.x;
    int h = hd >> 1, d = hd & 1;
    int m = threadIdx.x;
    __shared__ float2 pws[65 * 64];
    __shared__ float2 c2s[64];
    __shared__ float  Karr[64];

    int i = h * 64 + m;
    float dt = expf(log_dt[h]);
    float Are = A_re[i], Aim = A_im[i];
    float dr = dt * Are, di = dt * Aim;
    float er = expf(dr);
    float wr = er * cosf(di), wi = er * sinf(di);
    float em1r = wr - 1.0f, em1i = wi;
    float inv = 1.0f / (Are * Are + Aim * Aim);
    float qr = (em1r * Are + em1i * Aim) * inv;
    float qi = (em1i * Are - em1r * Aim) * inv;
    float Cr = C_re[d * HN + i], Ci = C_im[d * HN + i];
    float2 c2;
    c2.x = 2.0f * (Cr * qr - Ci * qi);
    c2.y = 2.0f * (Cr * qi + Ci * qr);
    c2s[m] = c2;
    float pr = 1.0f, pi = 0.0f;
    for (int k = 0; k < 64; ++k) {
        float2 p; p.x = pr; p.y = pi;
        pws[k * 64 + ((m + k) & 63)] = p;
        float t = pr * wr - pi * wi;
        pi = pr * wi + pi * wr;
        pr = t;
    }
    {
        float2 p; p.x = pr; p.y = pi;
        pws[64 * 64 + ((m + 64) & 63)] = p;
        Wc[hd * 64 + m] = p;
    }
    __syncthreads();
    {
        float kk = 0.f;
        for (int mm = 0; mm < 64; ++mm) {
            float2 c = c2s[mm];
            float2 pw = pws[m * 64 + ((mm + m) & 63)];
            kk += c.x * pw.x - c.y * pw.y;
        }
        Karr[m] = kk;
    }
    __syncthreads();
    unsigned short* mb = mats + (size_t)hd * MATS_PER;
    for (int i2 = 0; i2 < 32; ++i2) {
        int e0 = 2 * i2, e1 = e0 + 1;
        int k0 = d ? e0 : 63 - e0;
        int k1 = d ? e1 : 63 - e1;
        float2 p0 = pws[k0 * 64 + ((m + k0) & 63)];
        float2 p1 = pws[k1 * 64 + ((m + k1) & 63)];
        *(unsigned int*)(mb + WVT_OFS + (2 * m) * 64 + e0)     = pk2(p0.x, p1.x);
        *(unsigned int*)(mb + WVT_OFS + (2 * m + 1) * 64 + e0) = pk2(p0.y, p1.y);
    }
    for (int i2 = 0; i2 < 32; ++i2) {
        int e0 = 2 * i2, e1 = e0 + 1;
        float v0, v1;
        if (d == 0) {
            v0 = (e0 <= m) ? Karr[m - e0] : 0.f;
            v1 = (e1 <= m) ? Karr[m - e1] : 0.f;
        } else {
            v0 = (e0 > m) ? Karr[e0 - m - 1] : 0.f;
            v1 = (e1 > m) ? Karr[e1 - m - 1] : 0.f;
        }
        *(unsigned int*)(mb + TM_OFS + m * 64 + e0) = pk2(v0, v1);
    }
    {
        int kp = d ? (63 - m) : (m + 1);
        for (int mm = 0; mm < 64; ++mm) {
            float2 c = c2s[mm];
            float2 pw = pws[kp * 64 + ((mm + kp) & 63)];
            float vr = c.x * pw.x - c.y * pw.y;
            float vi = -(c.x * pw.y + c.y * pw.x);
            *(unsigned int*)(mb + E2T_OFS + m * 128 + 2 * mm) = pk2(vr, vi);
        }
    }
}

// ---------------------------------------------------------------------------
// Kernel 1b: W fp32 -> bf16
// ---------------------------------------------------------------------------
__global__ void __launch_bounds__(256) wbf_kernel(const float* __restrict__ W,
                                                  unsigned short* __restrict__ Wbf) {
    int i = (blockIdx.x * 256 + threadIdx.x) * 4;
    float4 v = *(const float4*)(W + i);
    uint2 u;
    u.x = pk2(v.x, v.y);
    u.y = pk2(v.z, v.w);
    *(uint2*)(Wbf + i) = u;
}

// ---------------------------------------------------------------------------
// Kernel 2: LayerNorm over channel dim H for each (b,l).
// ---------------------------------------------------------------------------
__global__ void __launch_bounds__(256) ln_kernel(const float* __restrict__ x,
                                                 const float* __restrict__ lnw,
                                                 const float* __restrict__ lnb,
                                                 float* __restrict__ z) {
    int b  = blockIdx.y;
    int l0 = blockIdx.x * 256;
    int t  = threadIdx.x;
    int hq = t >> 6, lo = t & 63;
    int l  = l0 + lo * 4;
    __shared__ float4 r1[4][64];
    __shared__ float4 r2[4][64];
    __shared__ float4 muS[64];
    __shared__ float4 rsS[64];
    const float* xb = x + (size_t)b * HL;
    float4 s1 = {0.f,0.f,0.f,0.f}, s2 = {0.f,0.f,0.f,0.f};
    #pragma unroll 4
    for (int hh = 0; hh < 64; ++hh) {
        int h = hq * 64 + hh;
        float4 v = *(const float4*)(xb + (size_t)h * L_ + l);
        s1.x += v.x; s1.y += v.y; s1.z += v.z; s1.w += v.w;
        s2.x += v.x*v.x; s2.y += v.y*v.y; s2.z += v.z*v.z; s2.w += v.w*v.w;
    }
    r1[hq][lo] = s1; r2[hq][lo] = s2;
    __syncthreads();
    if (t < 64) {
        float4 S1 = r1[0][t], S2 = r2[0][t];
        #pragma unroll
        for (int q = 1; q < 4; ++q) {
            float4 a = r1[q][t], c = r2[q][t];
            S1.x += a.x; S1.y += a.y; S1.z += a.z; S1.w += a.w;
            S2.x += c.x; S2.y += c.y; S2.z += c.z; S2.w += c.w;
        }
        const float invH = 1.0f / 256.0f;
        float4 mu, rs;
        mu.x = S1.x*invH; mu.y = S1.y*invH; mu.z = S1.z*invH; mu.w = S1.w*invH;
        rs.x = rsqrtf(S2.x*invH - mu.x*mu.x + 1e-5f);
        rs.y = rsqrtf(S2.y*invH - mu.y*mu.y + 1e-5f);
        rs.z = rsqrtf(S2.z*invH - mu.z*mu.z + 1e-5f);
        rs.w = rsqrtf(S2.w*invH - mu.w*mu.w + 1e-5f);
        muS[t] = mu; rsS[t] = rs;
    }
    __syncthreads();
    float4 mu = muS[lo], rs = rsS[lo];
    #pragma unroll 4
    for (int hh = 0; hh < 64; ++hh) {
        int h = hq * 64 + hh;
        float w = lnw[h], bb = lnb[h];
        float4 v = *(const float4*)(xb + (size_t)h * L_ + l);
        float4 zz;
        zz.x = (v.x - mu.x) * rs.x * w + bb;
        zz.y = (v.y - mu.y) * rs.y * w + bb;
        zz.z = (v.z - mu.z) * rs.z * w + bb;
        zz.w = (v.w - mu.w) * rs.w * w + bb;
        *(float4*)(z + (size_t)b * HL + (size_t)h * L_ + l) = zz;
    }
}

// ---------------------------------------------------------------------------
// Kernel 3: MFMA chunked S4D (same as R3, occupancy 2 -> 4 blocks/CU).
// ---------------------------------------------------------------------------
#define MFMA16(a,b,c) __builtin_amdgcn_mfma_f32_16x16x32_bf16((a),(b),(c),0,0,0)

__global__ void __launch_bounds__(256, 4) ssm_kernel(const float* __restrict__ z,
                                                     const unsigned short* __restrict__ mats,
                                                     const float2* __restrict__ Wc,
                                                     const float* __restrict__ D,
                                                     float* __restrict__ g) {
    int bh = blockIdx.x;
    int h  = bh & (H_ - 1);
    int t  = threadIdx.x;
    int w  = t >> 6, l = t & 63;
    int d  = w >> 1, p = w & 1;

    __shared__ unsigned int sZb[64 * 32];      // 8 KB
    __shared__ unsigned int sU[2][64 * 64];    // 32 KB

    const unsigned short* mb = mats + (size_t)(h * 2 + d) * MATS_PER;

    {
        int r = t >> 2, q = t & 3;
        const float* zp = z + (size_t)bh * L_ + r * 64 + q * 16;
        float4 v0 = *(const float4*)(zp + 0);
        float4 v1 = *(const float4*)(zp + 4);
        float4 v2 = *(const float4*)(zp + 8);
        float4 v3 = *(const float4*)(zp + 12);
        uint4 u0, u1;
        u0.x = pk2(v0.x, v0.y); u0.y = pk2(v0.z, v0.w);
        u0.z = pk2(v1.x, v1.y); u0.w = pk2(v1.z, v1.w);
        u1.x = pk2(v2.x, v2.y); u1.y = pk2(v2.z, v2.w);
        u1.z = pk2(v3.x, v3.y); u1.w = pk2(v3.z, v3.w);
        unsigned int base = r * 128 + q * 32;
        unsigned int sw = (r & 7) << 4;
        *(uint4*)((char*)sZb + ((base) ^ sw))      = u0;
        *(uint4*)((char*)sZb + ((base + 16) ^ sw)) = u1;
    }
    __syncthreads();

    bf16x8 za[4][2];
    int arow = l & 15;
    int koff = (l >> 4) * 8;
    #pragma unroll
    for (int cb = 0; cb < 4; ++cb) {
        int row = cb * 16 + arow;
        unsigned int sw = (row & 7) << 4;
        #pragma unroll
        for (int kb = 0; kb < 2; ++kb) {
            unsigned int byte = (row * 128 + (kb * 32 + koff) * 2) ^ sw;
            za[cb][kb] = *(bf16x8*)((char*)sZb + byte);
        }
    }

    #pragma unroll
    for (int mcb = 0; mcb < 4; ++mcb) {
        int mcblk = p * 4 + mcb;
        const unsigned short* wv = mb + WVT_OFS + (mcblk * 16 + arow) * 64 + koff;
        bf16x8 b0 = *(const bf16x8*)(wv);
        bf16x8 b1 = *(const bf16x8*)(wv + 32);
        #pragma unroll
        for (int cb = 0; cb < 4; ++cb) {
            f32x4 acc = {0.f, 0.f, 0.f, 0.f};
            acc = MFMA16(za[cb][0], b0, acc);
            acc = MFMA16(za[cb][1], b1, acc);
            int mc = mcblk * 16 + arow;
            #pragma unroll
            for (int rr = 0; rr < 4; ++rr) {
                int c = cb * 16 + (l >> 4) * 4 + rr;
                unsigned int byte = ((unsigned)(c * 256 + mc * 2)) ^ ((c & 7) << 4);
                *(unsigned short*)((char*)&sU[d][0] + byte) = bfr(acc[rr]);
            }
        }
    }
    __syncthreads();

    if (p == 0) {
        float2 w64 = Wc[(h * 2 + d) * 64 + l];
        float sr = 0.f, si = 0.f;
        if (d == 0) {
            for (int c = 0; c < 64; ++c) {
                unsigned int byte = ((unsigned)(c * 256 + l * 4)) ^ ((c & 7) << 4);
                unsigned int uu = *(unsigned int*)((char*)&sU[0][0] + byte);
                float ur = __uint_as_float(uu << 16);
                float ui = __uint_as_float(uu & 0xffff0000u);
                *(unsigned int*)((char*)&sU[0][0] + byte) = pk2(sr, si);
                float nsr = fmaf(w64.x, sr, fmaf(-w64.y, si, ur));
                float nsi = fmaf(w64.x, si, fmaf(w64.y, sr, ui));
                sr = nsr; si = nsi;
            }
        } else {
            for (int c = 63; c >= 0; --c) {
                unsigned int byte = ((unsigned)(c * 256 + l * 4)) ^ ((c & 7) << 4);
                unsigned int uu = *(unsigned int*)((char*)&sU[1][0] + byte);
                float ur = __uint_as_float(uu << 16);
                float ui = __uint_as_float(uu & 0xffff0000u);
                *(unsigned int*)((char*)&sU[1][0] + byte) = pk2(sr, si);
                float nsr = fmaf(w64.x, sr, fmaf(-w64.y, si, ur));
                float nsi = fmaf(w64.x, si, fmaf(w64.y, sr, ui));
                sr = nsr; si = nsi;
            }
        }
    }
    __syncthreads();

    f32x4 yacc[2][4];
    #pragma unroll
    for (int jb = 0; jb < 2; ++jb) {
        int jblk = p * 2 + jb;
        const unsigned short* tm = mb + TM_OFS + (jblk * 16 + arow) * 64 + koff;
        bf16x8 tb0 = *(const bf16x8*)(tm);
        bf16x8 tb1 = *(const bf16x8*)(tm + 32);
        const unsigned short* et = mb + E2T_OFS + (jblk * 16 + arow) * 128 + koff;
        bf16x8 eb0 = *(const bf16x8*)(et);
        bf16x8 eb1 = *(const bf16x8*)(et + 32);
        bf16x8 eb2 = *(const bf16x8*)(et + 64);
        bf16x8 eb3 = *(const bf16x8*)(et + 96);
        #pragma unroll
        for (int cb = 0; cb < 4; ++cb) {
            f32x4 acc = {0.f, 0.f, 0.f, 0.f};
            acc = MFMA16(za[cb][0], tb0, acc);
            acc = MFMA16(za[cb][1], tb1, acc);
            int row = cb * 16 + arow;
            unsigned int sw = (row & 7) << 4;
            bf16x8 sa0 = *(bf16x8*)((char*)&sU[d][0] + (((unsigned)(row * 256 + (0 * 32 + koff) * 2)) ^ sw));
            bf16x8 sa1 = *(bf16x8*)((char*)&sU[d][0] + (((unsigned)(row * 256 + (1 * 32 + koff) * 2)) ^ sw));
            bf16x8 sa2 = *(bf16x8*)((char*)&sU[d][0] + (((unsigned)(row * 256 + (2 * 32 + koff) * 2)) ^ sw));
            bf16x8 sa3 = *(bf16x8*)((char*)&sU[d][0] + (((unsigned)(row * 256 + (3 * 32 + koff) * 2)) ^ sw));
            acc = MFMA16(sa0, eb0, acc);
            acc = MFMA16(sa1, eb1, acc);
            acc = MFMA16(sa2, eb2, acc);
            acc = MFMA16(sa3, eb3, acc);
            yacc[jb][cb] = acc;
        }
    }
    __syncthreads();

    float* Yb = (float*)&sU[0][0];
    if (d == 1) {
        #pragma unroll
        for (int jb = 0; jb < 2; ++jb) {
            int j = (p * 2 + jb) * 16 + arow;
            #pragma unroll
            for (int cb = 0; cb < 4; ++cb) {
                #pragma unroll
                for (int rr = 0; rr < 4; ++rr) {
                    int c = cb * 16 + (l >> 4) * 4 + rr;
                    Yb[c * 66 + j] = yacc[jb][cb][rr];
                }
            }
        }
    }
    __syncthreads();
    if (d == 0) {
        float dv = D[h];
        float* go = g + (size_t)bh * L_;
        #pragma unroll
        for (int jb = 0; jb < 2; ++jb) {
            int j = (p * 2 + jb) * 16 + arow;
            #pragma unroll
            for (int cb = 0; cb < 4; ++cb) {
                #pragma unroll
                for (int rr = 0; rr < 4; ++rr) {
                    int c = cb * 16 + (l >> 4) * 4 + rr;
                    unsigned int zbyte = ((unsigned)(c * 128 + j * 2)) ^ ((c & 7) << 4);
                    float zv = ubf(*(unsigned short*)((char*)sZb + zbyte));
                    float y = yacc[jb][cb][rr] + Yb[c * 66 + j] + dv * zv;
                    float inner = 0.7978845608028654f * (y + 0.044715f * y * y * y);
                    go[c * 64 + j] = 0.5f * y * (1.0f + tanhf(inner));
                }
            }
        }
    }
}

// ---------------------------------------------------------------------------
// Kernel 4: transpose g[b][h][l] f32 -> gT[b][l][h] bf16 (LDS swizzled)
// element (l,h) at LDS byte l*512 + (h*2 ^ ((l&7)<<4))
// ---------------------------------------------------------------------------
__global__ void __launch_bounds__(256, 8) gt_kernel(const float* __restrict__ g,
                                                    unsigned short* __restrict__ gT) {
    int b  = blockIdx.y;
    int l0 = blockIdx.x * 32;
    int t  = threadIdx.x;
    __shared__ unsigned short lT[32 * 256];   // 16 KB
    const float* gp = g + ((size_t)b * H_ + t) * L_ + l0;
    float4 v[8];
    #pragma unroll
    for (int j = 0; j < 8; ++j) v[j] = *(const float4*)(gp + j * 4);
    #pragma unroll
    for (int j = 0; j < 8; ++j) {
        #pragma unroll
        for (int e2 = 0; e2 < 4; ++e2) {
            int ll = j * 4 + e2;
            float vv = (e2 == 0) ? v[j].x : (e2 == 1) ? v[j].y : (e2 == 2) ? v[j].z : v[j].w;
            *(unsigned short*)((char*)lT + ll * 512 + ((t * 2) ^ ((ll & 7) << 4))) = bfr(vv);
        }
    }
    __syncthreads();
    int l = t >> 3, seg = t & 7;
    unsigned short* dst = gT + ((size_t)b * L_ + l0 + l) * 256 + seg * 32;
    #pragma unroll
    for (int j = 0; j < 4; ++j) {
        uint4 u = *(const uint4*)((char*)lT + l * 512 + (((seg * 64 + j * 16)) ^ ((l & 7) << 4)));
        *(uint4*)(dst + j * 8) = u;
    }
}

// ---------------------------------------------------------------------------
// Kernel 5: out[b,o,l] = x + b_out[o] + sum_h W[o,h]*g[b,h,l], bf16 MFMA.
// A = gT[l][k], B = Wbf[o][k], D[l][o]; 128x128 tile, K=256 in 4 steps.
// LDS rows 128B, XOR-swizzle ((row&7)<<4); epilogue transpose via LDS.
// ---------------------------------------------------------------------------
__global__ void __launch_bounds__(256, 3) outproj_kernel(
        const unsigned short* __restrict__ gT,
        const unsigned short* __restrict__ Wbf,
        const float* __restrict__ x,
        const float* __restrict__ bias,
        float* __restrict__ out) {
    int b  = blockIdx.z;
    int o0 = blockIdx.y * 128;
    int l0 = blockIdx.x * 128;
    int t  = threadIdx.x;
    int w  = t >> 6, lane = t & 63;
    int wr = w >> 1, wc = w & 1;
    int l15 = lane & 15, q = lane >> 4;

    __shared__ __align__(16) char lds[34816];
    unsigned short* At = (unsigned short*)lds;            // [128 l][64 k] swizzled
    unsigned short* Bt = (unsigned short*)(lds + 16384);  // [128 o][64 k] swizzled

    f32x4 acc[4][4];
    #pragma unroll
    for (int i = 0; i < 4; ++i)
        #pragma unroll
        for (int j = 0; j < 4; ++j) acc[i][j] = (f32x4){0.f, 0.f, 0.f, 0.f};

    const unsigned short* gTb = gT + ((size_t)b * L_ + l0) * 256;
    const unsigned short* Wb0 = Wbf + (size_t)o0 * 256;
    unsigned int swz = (unsigned)(l15 & 7) << 4;

    for (int kt = 0; kt < 4; ++kt) {
        int k0 = kt * 64;
        // stage A and B (pre-swizzled source, linear LDS)
        #pragma unroll
        for (int s = 0; s < 4; ++s) {
            int id = (w * 4 + s) * 64 + lane;   // 0..1023
            int row = id >> 3, ch = id & 7;
            int chl = ch ^ (row & 7);
            uint4 va = *(const uint4*)(gTb + (size_t)row * 256 + k0 + chl * 8);
            uint4 vb = *(const uint4*)(Wb0 + (size_t)row * 256 + k0 + chl * 8);
            *(uint4*)(At + id * 8) = va;
            *(uint4*)(Bt + id * 8) = vb;
        }
        __syncthreads();
        #pragma unroll
        for (int kk = 0; kk < 2; ++kk) {
            bf16x8 af[4], bfr_[4];
            #pragma unroll
            for (int rb = 0; rb < 4; ++rb) {
                int li = wr * 64 + rb * 16 + l15;
                af[rb] = *(const bf16x8*)((char*)At + li * 128 + (((kk * 64 + q * 16)) ^ swz));
                int oi = wc * 64 + rb * 16 + l15;
                bfr_[rb] = *(const bf16x8*)((char*)Bt + oi * 128 + (((kk * 64 + q * 16)) ^ swz));
            }
            #pragma unroll
            for (int rb = 0; rb < 4; ++rb)
                #pragma unroll
                for (int cb = 0; cb < 4; ++cb)
                    acc[rb][cb] = MFMA16(af[rb], bfr_[cb], acc[rb][cb]);
        }
        __syncthreads();
    }

    // epilogue: two o-half passes through LDS transpose [64 o][132 l] f32
    float* Eb = (float*)lds;
    for (int pp = 0; pp < 2; ++pp) {
        if (wc == pp) {
            #pragma unroll
            for (int cb = 0; cb < 4; ++cb) {
                int o_loc = cb * 16 + l15;
                unsigned int esw = (unsigned)(o_loc & 7) << 4;
                #pragma unroll
                for (int rb = 0; rb < 4; ++rb) {
                    int colbase = wr * 64 + rb * 16 + q * 4;
                    #pragma unroll
                    for (int r = 0; r < 4; ++r) {
                        int col = colbase + r;
                        *(float*)((char*)Eb + o_loc * 528 + (((unsigned)(col * 4)) ^ esw)) =
                            acc[rb][cb][r];
                    }
                }
            }
        }
        __syncthreads();
        int o_loc = t >> 2, lseg = t & 3;
        int o = o0 + pp * 64 + o_loc;
        float bo = bias[o];
        unsigned int esw = (unsigned)(o_loc & 7) << 4;
        size_t off = ((size_t)b * H_ + o) * L_ + l0 + lseg * 32;
        const float* xr = x + off;
        float* orow = out + off;
        #pragma unroll
        for (int j = 0; j < 8; ++j) {
            float4 e = *(const float4*)((char*)Eb + o_loc * 528 +
                                        (((unsigned)(lseg * 128 + j * 16)) ^ esw));
            float4 xv = *(const float4*)(xr + j * 4);
            float4 ov;
            ov.x = xv.x + bo + e.x;
            ov.y = xv.y + bo + e.y;
            ov.z = xv.z + bo + e.z;
            ov.w = xv.w + bo + e.w;
            *(float4*)(orow + j * 4) = ov;
        }
        __syncthreads();
    }
}

// ---------------------------------------------------------------------------
extern "C" void kernel_launch(void* const* d_in, const int* in_sizes, int n_in,
                              void* d_out, int out_size, void* d_ws, size_t ws_size,
                              hipStream_t stream) {
    const float* x      = (const float*)d_in[0];
    const float* log_dt = (const float*)d_in[1];
    const float* A_re   = (const float*)d_in[2];
    const float* A_im   = (const float*)d_in[3];
    const float* C_re   = (const float*)d_in[4];
    const float* C_im   = (const float*)d_in[5];
    const float* D      = (const float*)d_in[6];
    const float* lnw    = (const float*)d_in[7];
    const float* lnb    = (const float*)d_in[8];
    const float* W      = (const float*)d_in[9];
    const float* bout   = (const float*)d_in[10];
    float* out = (float*)d_out;
    float* ws  = (float*)d_ws;

    float* z = ws;                                   // BHL f32 (aliased by gT later)
    float* g = ws + (size_t)BHL;                     // BHL f32
    unsigned short* mats = (unsigned short*)(ws + 2 * (size_t)BHL);
    float2* Wc = (float2*)(ws + 2 * (size_t)BHL + (512 * (size_t)MATS_PER) / 2);
    unsigned short* Wbf = (unsigned short*)(ws + 2 * (size_t)BHL + (512 * (size_t)MATS_PER) / 2 + 2 * 512 * 64);
    unsigned short* gT = (unsigned short*)z;         // z dead after ssm

    mats_kernel<<<512, 64, 0, stream>>>(log_dt, A_re, A_im, C_re, C_im, mats, Wc);
    wbf_kernel<<<64, 256, 0, stream>>>(W, Wbf);
    ln_kernel<<<dim3(L_ / 256, B_), 256, 0, stream>>>(x, lnw, lnb, z);
    ssm_kernel<<<B_ * H_, 256, 0, stream>>>(z, mats, Wc, D, g);
    gt_kernel<<<dim3(L_ / 32, B_), 256, 0, stream>>>(g, gT);
    outproj_kernel<<<dim3(L_ / 128, H_ / 128, B_), 256, 0, stream>>>(gT, Wbf, x, bout, out);
}

// Round 6
// 222.976 us; speedup vs baseline: 3.7918x; 1.0241x over previous
//
#include <hip/hip_runtime.h>
#include <math.h>

#define B_ 16
#define H_ 256
#define L_ 4096
#define N_ 64
#define HN (H_*N_)
#define HL (H_*L_)
#define BHL (B_*H_*L_)

#define WVT_OFS 0
#define TM_OFS  8192
#define E2T_OFS 12288
#define MATS_PER 20480

typedef short bf16x8 __attribute__((ext_vector_type(8)));
typedef float f32x4  __attribute__((ext_vector_type(4)));

__device__ __forceinline__ unsigned int pk2(float a, float b) {
    return ((__float_as_uint(a) + 0x8000u) >> 16) |
           ((__float_as_uint(b) + 0x8000u) & 0xffff0000u);
}
__device__ __forceinline__ unsigned short bfr(float a) {
    return (unsigned short)((__float_as_uint(a) + 0x8000u) >> 16);
}
__device__ __forceinline__ float ubf(unsigned short u) {
    return __uint_as_float(((unsigned int)u) << 16);
}

// ---------------------------------------------------------------------------
// Kernel 1: build per-(h,dir) matrices + w^64. 1 wave per (h,dir).
// ---------------------------------------------------------------------------
__global__ void __launch_bounds__(64) mats_kernel(const float* __restrict__ log_dt,
                                                  const float* __restrict__ A_re,
                                                  const float* __restrict__ A_im,
                                                  const float* __restrict__ C_re,
                                                  const float* __restrict__ C_im,
                                                  unsigned short* __restrict__ mats,
                                                  float2* __restrict__ Wc) {
    int hd = blockIdx.x;
    int h = hd >> 1, d = hd & 1;
    int m = threadIdx.x;
    __shared__ float2 pws[65 * 64];
    __shared__ float2 c2s[64];
    __shared__ float  Karr[64];

    int i = h * 64 + m;
    float dt = expf(log_dt[h]);
    float Are = A_re[i], Aim = A_im[i];
    float dr = dt * Are, di = dt * Aim;
    float er = expf(dr);
    float wr = er * cosf(di), wi = er * sinf(di);
    float em1r = wr - 1.0f, em1i = wi;
    float inv = 1.0f / (Are * Are + Aim * Aim);
    float qr = (em1r * Are + em1i * Aim) * inv;
    float qi = (em1i * Are - em1r * Aim) * inv;
    float Cr = C_re[d * HN + i], Ci = C_im[d * HN + i];
    float2 c2;
    c2.x = 2.0f * (Cr * qr - Ci * qi);
    c2.y = 2.0f * (Cr * qi + Ci * qr);
    c2s[m] = c2;
    float pr = 1.0f, pi = 0.0f;
    for (int k = 0; k < 64; ++k) {
        float2 p; p.x = pr; p.y = pi;
        pws[k * 64 + ((m + k) & 63)] = p;
        float t = pr * wr - pi * wi;
        pi = pr * wi + pi * wr;
        pr = t;
    }
    {
        float2 p; p.x = pr; p.y = pi;
        pws[64 * 64 + ((m + 64) & 63)] = p;
        Wc[hd * 64 + m] = p;
    }
    __syncthreads();
    {
        float kk = 0.f;
        for (int mm = 0; mm < 64; ++mm) {
            float2 c = c2s[mm];
            float2 pw = pws[m * 64 + ((mm + m) & 63)];
            kk += c.x * pw.x - c.y * pw.y;
        }
        Karr[m] = kk;
    }
    __syncthreads();
    unsigned short* mb = mats + (size_t)hd * MATS_PER;
    for (int i2 = 0; i2 < 32; ++i2) {
        int e0 = 2 * i2, e1 = e0 + 1;
        int k0 = d ? e0 : 63 - e0;
        int k1 = d ? e1 : 63 - e1;
        float2 p0 = pws[k0 * 64 + ((m + k0) & 63)];
        float2 p1 = pws[k1 * 64 + ((m + k1) & 63)];
        *(unsigned int*)(mb + WVT_OFS + (2 * m) * 64 + e0)     = pk2(p0.x, p1.x);
        *(unsigned int*)(mb + WVT_OFS + (2 * m + 1) * 64 + e0) = pk2(p0.y, p1.y);
    }
    for (int i2 = 0; i2 < 32; ++i2) {
        int e0 = 2 * i2, e1 = e0 + 1;
        float v0, v1;
        if (d == 0) {
            v0 = (e0 <= m) ? Karr[m - e0] : 0.f;
            v1 = (e1 <= m) ? Karr[m - e1] : 0.f;
        } else {
            v0 = (e0 > m) ? Karr[e0 - m - 1] : 0.f;
            v1 = (e1 > m) ? Karr[e1 - m - 1] : 0.f;
        }
        *(unsigned int*)(mb + TM_OFS + m * 64 + e0) = pk2(v0, v1);
    }
    {
        int kp = d ? (63 - m) : (m + 1);
        for (int mm = 0; mm < 64; ++mm) {
            float2 c = c2s[mm];
            float2 pw = pws[kp * 64 + ((mm + kp) & 63)];
            float vr = c.x * pw.x - c.y * pw.y;
            float vi = -(c.x * pw.y + c.y * pw.x);
            *(unsigned int*)(mb + E2T_OFS + m * 128 + 2 * mm) = pk2(vr, vi);
        }
    }
}

// ---------------------------------------------------------------------------
// Kernel 1b: W fp32 -> bf16
// ---------------------------------------------------------------------------
__global__ void __launch_bounds__(256) wbf_kernel(const float* __restrict__ W,
                                                  unsigned short* __restrict__ Wbf) {
    int i = (blockIdx.x * 256 + threadIdx.x) * 4;
    float4 v = *(const float4*)(W + i);
    uint2 u;
    u.x = pk2(v.x, v.y);
    u.y = pk2(v.z, v.w);
    *(uint2*)(Wbf + i) = u;
}

// ---------------------------------------------------------------------------
// Kernel 2: LayerNorm over channel dim H; writes z as bf16.
// ---------------------------------------------------------------------------
__global__ void __launch_bounds__(256) ln_kernel(const float* __restrict__ x,
                                                 const float* __restrict__ lnw,
                                                 const float* __restrict__ lnb,
                                                 unsigned short* __restrict__ zb) {
    int b  = blockIdx.y;
    int l0 = blockIdx.x * 256;
    int t  = threadIdx.x;
    int hq = t >> 6, lo = t & 63;
    int l  = l0 + lo * 4;
    __shared__ float4 r1[4][64];
    __shared__ float4 r2[4][64];
    __shared__ float4 muS[64];
    __shared__ float4 rsS[64];
    const float* xb = x + (size_t)b * HL;
    float4 s1 = {0.f,0.f,0.f,0.f}, s2 = {0.f,0.f,0.f,0.f};
    #pragma unroll 4
    for (int hh = 0; hh < 64; ++hh) {
        int h = hq * 64 + hh;
        float4 v = *(const float4*)(xb + (size_t)h * L_ + l);
        s1.x += v.x; s1.y += v.y; s1.z += v.z; s1.w += v.w;
        s2.x += v.x*v.x; s2.y += v.y*v.y; s2.z += v.z*v.z; s2.w += v.w*v.w;
    }
    r1[hq][lo] = s1; r2[hq][lo] = s2;
    __syncthreads();
    if (t < 64) {
        float4 S1 = r1[0][t], S2 = r2[0][t];
        #pragma unroll
        for (int q = 1; q < 4; ++q) {
            float4 a = r1[q][t], c = r2[q][t];
            S1.x += a.x; S1.y += a.y; S1.z += a.z; S1.w += a.w;
            S2.x += c.x; S2.y += c.y; S2.z += c.z; S2.w += c.w;
        }
        const float invH = 1.0f / 256.0f;
        float4 mu, rs;
        mu.x = S1.x*invH; mu.y = S1.y*invH; mu.z = S1.z*invH; mu.w = S1.w*invH;
        rs.x = rsqrtf(S2.x*invH - mu.x*mu.x + 1e-5f);
        rs.y = rsqrtf(S2.y*invH - mu.y*mu.y + 1e-5f);
        rs.z = rsqrtf(S2.z*invH - mu.z*mu.z + 1e-5f);
        rs.w = rsqrtf(S2.w*invH - mu.w*mu.w + 1e-5f);
        muS[t] = mu; rsS[t] = rs;
    }
    __syncthreads();
    float4 mu = muS[lo], rs = rsS[lo];
    #pragma unroll 4
    for (int hh = 0; hh < 64; ++hh) {
        int h = hq * 64 + hh;
        float w = lnw[h], bb = lnb[h];
        float4 v = *(const float4*)(xb + (size_t)h * L_ + l);
        float4 zz;
        zz.x = (v.x - mu.x) * rs.x * w + bb;
        zz.y = (v.y - mu.y) * rs.y * w + bb;
        zz.z = (v.z - mu.z) * rs.z * w + bb;
        zz.w = (v.w - mu.w) * rs.w * w + bb;
        uint2 u;
        u.x = pk2(zz.x, zz.y);
        u.y = pk2(zz.z, zz.w);
        *(uint2*)(zb + (size_t)b * HL + (size_t)h * L_ + l) = u;
    }
}

// ---------------------------------------------------------------------------
// Kernel 3: MFMA chunked S4D. z bf16 in via global_load_lds (pre-swizzled
// source), g bf16 out via LDS-assembled coalesced stores.
// ---------------------------------------------------------------------------
#define MFMA16(a,b,c) __builtin_amdgcn_mfma_f32_16x16x32_bf16((a),(b),(c),0,0,0)
#define SU_BASE 8192
#define GST_BASE 32768

__global__ void __launch_bounds__(256, 4) ssm_kernel(const unsigned short* __restrict__ zb,
                                                     const unsigned short* __restrict__ mats,
                                                     const float2* __restrict__ Wc,
                                                     const float* __restrict__ D,
                                                     unsigned short* __restrict__ gb) {
    int bh = blockIdx.x;
    int h  = bh & (H_ - 1);
    int t  = threadIdx.x;
    int w  = t >> 6, l = t & 63;
    int d  = w >> 1, p = w & 1;

    __shared__ __align__(16) char smem[40960];

    const unsigned short* mb = mats + (size_t)(h * 2 + d) * MATS_PER;

    // ---- stage z via global_load_lds (linear LDS dest, swizzled source) ----
    {
        const char* zrow = (const char*)(zb + (size_t)bh * L_);
        #pragma unroll
        for (int k = 0; k < 2; ++k) {
            int row = w * 16 + k * 8 + (l >> 3);
            int chunk = (l & 7) ^ (row & 7);
            const char* src = zrow + row * 128 + chunk * 16;
            __builtin_amdgcn_global_load_lds(
                (const __attribute__((address_space(1))) unsigned int*)src,
                (__attribute__((address_space(3))) unsigned int*)(smem + w * 2048 + k * 1024),
                16, 0, 0);
        }
    }
    __syncthreads();

    // ---- load Z A-frags ----
    bf16x8 za[4][2];
    int arow = l & 15;
    int koff = (l >> 4) * 8;
    #pragma unroll
    for (int cb = 0; cb < 4; ++cb) {
        int row = cb * 16 + arow;
        unsigned int sw = (row & 7) << 4;
        #pragma unroll
        for (int kb = 0; kb < 2; ++kb) {
            unsigned int byte = (unsigned)(row * 128 + (kb * 32 + koff) * 2) ^ sw;
            za[cb][kb] = *(bf16x8*)(smem + byte);
        }
    }

    // ---- M1: U = Z * Wv ----
    char* sUd = smem + SU_BASE + d * 16384;
    #pragma unroll
    for (int mcb = 0; mcb < 4; ++mcb) {
        int mcblk = p * 4 + mcb;
        const unsigned short* wv = mb + WVT_OFS + (mcblk * 16 + arow) * 64 + koff;
        bf16x8 b0 = *(const bf16x8*)(wv);
        bf16x8 b1 = *(const bf16x8*)(wv + 32);
        #pragma unroll
        for (int cb = 0; cb < 4; ++cb) {
            f32x4 acc = {0.f, 0.f, 0.f, 0.f};
            acc = MFMA16(za[cb][0], b0, acc);
            acc = MFMA16(za[cb][1], b1, acc);
            int mc = mcblk * 16 + arow;
            #pragma unroll
            for (int rr = 0; rr < 4; ++rr) {
                int c = cb * 16 + (l >> 4) * 4 + rr;
                unsigned int byte = ((unsigned)(c * 256 + mc * 2)) ^ ((c & 7) << 4);
                *(unsigned short*)(sUd + byte) = bfr(acc[rr]);
            }
        }
    }
    __syncthreads();

    // ---- scan over 64 chunks (p==0 waves; lane = mode) ----
    if (p == 0) {
        float2 w64 = Wc[(h * 2 + d) * 64 + l];
        float sr = 0.f, si = 0.f;
        if (d == 0) {
            for (int c = 0; c < 64; ++c) {
                unsigned int byte = ((unsigned)(c * 256 + l * 4)) ^ ((c & 7) << 4);
                unsigned int uu = *(unsigned int*)(sUd + byte);
                float ur = __uint_as_float(uu << 16);
                float ui = __uint_as_float(uu & 0xffff0000u);
                *(unsigned int*)(sUd + byte) = pk2(sr, si);
                float nsr = fmaf(w64.x, sr, fmaf(-w64.y, si, ur));
                float nsi = fmaf(w64.x, si, fmaf(w64.y, sr, ui));
                sr = nsr; si = nsi;
            }
        } else {
            for (int c = 63; c >= 0; --c) {
                unsigned int byte = ((unsigned)(c * 256 + l * 4)) ^ ((c & 7) << 4);
                unsigned int uu = *(unsigned int*)(sUd + byte);
                float ur = __uint_as_float(uu << 16);
                float ui = __uint_as_float(uu & 0xffff0000u);
                *(unsigned int*)(sUd + byte) = pk2(sr, si);
                float nsr = fmaf(w64.x, sr, fmaf(-w64.y, si, ur));
                float nsi = fmaf(w64.x, si, fmaf(w64.y, sr, ui));
                sr = nsr; si = nsi;
            }
        }
    }
    __syncthreads();

    // ---- M2+M3: Y = Z*T^T + Sb*E2^T ----
    f32x4 yacc[2][4];
    #pragma unroll
    for (int jb = 0; jb < 2; ++jb) {
        int jblk = p * 2 + jb;
        const unsigned short* tm = mb + TM_OFS + (jblk * 16 + arow) * 64 + koff;
        bf16x8 tb0 = *(const bf16x8*)(tm);
        bf16x8 tb1 = *(const bf16x8*)(tm + 32);
        const unsigned short* et = mb + E2T_OFS + (jblk * 16 + arow) * 128 + koff;
        bf16x8 eb0 = *(const bf16x8*)(et);
        bf16x8 eb1 = *(const bf16x8*)(et + 32);
        bf16x8 eb2 = *(const bf16x8*)(et + 64);
        bf16x8 eb3 = *(const bf16x8*)(et + 96);
        #pragma unroll
        for (int cb = 0; cb < 4; ++cb) {
            f32x4 acc = {0.f, 0.f, 0.f, 0.f};
            acc = MFMA16(za[cb][0], tb0, acc);
            acc = MFMA16(za[cb][1], tb1, acc);
            int row = cb * 16 + arow;
            unsigned int sw = (row & 7) << 4;
            bf16x8 sa0 = *(bf16x8*)(sUd + (((unsigned)(row * 256 + (0 * 32 + koff) * 2)) ^ sw));
            bf16x8 sa1 = *(bf16x8*)(sUd + (((unsigned)(row * 256 + (1 * 32 + koff) * 2)) ^ sw));
            bf16x8 sa2 = *(bf16x8*)(sUd + (((unsigned)(row * 256 + (2 * 32 + koff) * 2)) ^ sw));
            bf16x8 sa3 = *(bf16x8*)(sUd + (((unsigned)(row * 256 + (3 * 32 + koff) * 2)) ^ sw));
            acc = MFMA16(sa0, eb0, acc);
            acc = MFMA16(sa1, eb1, acc);
            acc = MFMA16(sa2, eb2, acc);
            acc = MFMA16(sa3, eb3, acc);
            yacc[jb][cb] = acc;
        }
    }
    __syncthreads();

    // ---- exchange bwd Y; combine + GELU into gstage; coalesced store ----
    float* Yb = (float*)(smem + SU_BASE);
    if (d == 1) {
        #pragma unroll
        for (int jb = 0; jb < 2; ++jb) {
            int j = (p * 2 + jb) * 16 + arow;
            #pragma unroll
            for (int cb = 0; cb < 4; ++cb) {
                #pragma unroll
                for (int rr = 0; rr < 4; ++rr) {
                    int c = cb * 16 + (l >> 4) * 4 + rr;
                    Yb[c * 66 + j] = yacc[jb][cb][rr];
                }
            }
        }
    }
    __syncthreads();
    if (d == 0) {
        float dv = D[h];
        #pragma unroll
        for (int jb = 0; jb < 2; ++jb) {
            int j = (p * 2 + jb) * 16 + arow;
            #pragma unroll
            for (int cb = 0; cb < 4; ++cb) {
                #pragma unroll
                for (int rr = 0; rr < 4; ++rr) {
                    int c = cb * 16 + (l >> 4) * 4 + rr;
                    unsigned int zbyte = ((unsigned)(c * 128 + j * 2)) ^ ((c & 7) << 4);
                    float zv = ubf(*(unsigned short*)(smem + zbyte));
                    float y = yacc[jb][cb][rr] + Yb[c * 66 + j] + dv * zv;
                    float inner = 0.7978845608028654f * (y + 0.044715f * y * y * y);
                    float gv = 0.5f * y * (1.0f + tanhf(inner));
                    *(unsigned short*)(smem + GST_BASE + zbyte) = bfr(gv);
                }
            }
        }
    }
    __syncthreads();
    {
        int c2 = t >> 2, s2 = t & 3;
        unsigned int rsw = (c2 & 7) << 4;
        char* go = (char*)(gb + (size_t)bh * L_);
        uint4 a0 = *(const uint4*)(smem + GST_BASE + (((unsigned)(c2 * 128 + s2 * 32)) ^ rsw));
        uint4 a1 = *(const uint4*)(smem + GST_BASE + (((unsigned)(c2 * 128 + s2 * 32 + 16)) ^ rsw));
        *(uint4*)(go + c2 * 128 + s2 * 32)      = a0;
        *(uint4*)(go + c2 * 128 + s2 * 32 + 16) = a1;
    }
}

// ---------------------------------------------------------------------------
// Kernel 4: transpose g[b][h][l] bf16 -> gT[b][l][h] bf16 via LDS.
// ---------------------------------------------------------------------------
__global__ void __launch_bounds__(256, 4) gt_kernel(const unsigned short* __restrict__ gb,
                                                    unsigned short* __restrict__ gT) {
    int b  = blockIdx.y;
    int l0 = blockIdx.x * 64;
    int t  = threadIdx.x;
    __shared__ __align__(16) char lT[64 * 512];   // 32 KB: [l][h] bf16 rows 512 B
    const unsigned short* gp = gb + ((size_t)b * H_ + t) * L_ + l0;
    uint4 v[8];
    #pragma unroll
    for (int j8 = 0; j8 < 8; ++j8) v[j8] = *(const uint4*)(gp + j8 * 8);
    #pragma unroll
    for (int j8 = 0; j8 < 8; ++j8) {
        #pragma unroll
        for (int e = 0; e < 8; ++e) {
            int l = j8 * 8 + e;
            unsigned short val = ((const unsigned short*)&v[j8])[e];
            *(unsigned short*)(lT + (((unsigned)(l * 512 + t * 2)) ^ ((l & 7) << 4))) = val;
        }
    }
    __syncthreads();
    int l = t >> 2, seg = t & 3;
    unsigned short* dst = gT + ((size_t)b * L_ + l0 + l) * 256 + seg * 64;
    unsigned int sw = (l & 7) << 4;
    #pragma unroll
    for (int j = 0; j < 8; ++j) {     // FIX: 8 uint4 per thread (was 4 — half of gT stale)
        uint4 u = *(const uint4*)(lT + (((unsigned)(l * 512 + seg * 128 + j * 16)) ^ sw));
        *(uint4*)(dst + j * 8) = u;
    }
}

// ---------------------------------------------------------------------------
// Kernel 5: out[b,o,l] = x + b_out[o] + sum_h W[o,h]*g[b,h,l], bf16 MFMA.
// ---------------------------------------------------------------------------
__global__ void __launch_bounds__(256, 3) outproj_kernel(
        const unsigned short* __restrict__ gT,
        const unsigned short* __restrict__ Wbf,
        const float* __restrict__ x,
        const float* __restrict__ bias,
        float* __restrict__ out) {
    int b  = blockIdx.z;
    int o0 = blockIdx.y * 128;
    int l0 = blockIdx.x * 128;
    int t  = threadIdx.x;
    int w  = t >> 6, lane = t & 63;
    int wr = w >> 1, wc = w & 1;
    int l15 = lane & 15, q = lane >> 4;

    __shared__ __align__(16) char lds[34816];
    unsigned short* At = (unsigned short*)lds;
    unsigned short* Bt = (unsigned short*)(lds + 16384);

    f32x4 acc[4][4];
    #pragma unroll
    for (int i = 0; i < 4; ++i)
        #pragma unroll
        for (int j = 0; j < 4; ++j) acc[i][j] = (f32x4){0.f, 0.f, 0.f, 0.f};

    const unsigned short* gTb = gT + ((size_t)b * L_ + l0) * 256;
    const unsigned short* Wb0 = Wbf + (size_t)o0 * 256;
    unsigned int swz = (unsigned)(l15 & 7) << 4;

    for (int kt = 0; kt < 4; ++kt) {
        int k0 = kt * 64;
        #pragma unroll
        for (int s = 0; s < 4; ++s) {
            int id = (w * 4 + s) * 64 + lane;
            int row = id >> 3, ch = id & 7;
            int chl = ch ^ (row & 7);
            uint4 va = *(const uint4*)(gTb + (size_t)row * 256 + k0 + chl * 8);
            uint4 vb = *(const uint4*)(Wb0 + (size_t)row * 256 + k0 + chl * 8);
            *(uint4*)(At + id * 8) = va;
            *(uint4*)(Bt + id * 8) = vb;
        }
        __syncthreads();
        #pragma unroll
        for (int kk = 0; kk < 2; ++kk) {
            bf16x8 af[4], bfr_[4];
            #pragma unroll
            for (int rb = 0; rb < 4; ++rb) {
                int li = wr * 64 + rb * 16 + l15;
                af[rb] = *(const bf16x8*)((char*)At + li * 128 + (((kk * 64 + q * 16)) ^ swz));
                int oi = wc * 64 + rb * 16 + l15;
                bfr_[rb] = *(const bf16x8*)((char*)Bt + oi * 128 + (((kk * 64 + q * 16)) ^ swz));
            }
            #pragma unroll
            for (int rb = 0; rb < 4; ++rb)
                #pragma unroll
                for (int cb = 0; cb < 4; ++cb)
                    acc[rb][cb] = MFMA16(af[rb], bfr_[cb], acc[rb][cb]);
        }
        __syncthreads();
    }

    float* Eb = (float*)lds;
    for (int pp = 0; pp < 2; ++pp) {
        if (wc == pp) {
            #pragma unroll
            for (int cb = 0; cb < 4; ++cb) {
                int o_loc = cb * 16 + l15;
                unsigned int esw = (unsigned)(o_loc & 7) << 4;
                #pragma unroll
                for (int rb = 0; rb < 4; ++rb) {
                    int colbase = wr * 64 + rb * 16 + q * 4;
                    #pragma unroll
                    for (int r = 0; r < 4; ++r) {
                        int col = colbase + r;
                        *(float*)((char*)Eb + o_loc * 528 + (((unsigned)(col * 4)) ^ esw)) =
                            acc[rb][cb][r];
                    }
                }
            }
        }
        __syncthreads();
        int o_loc = t >> 2, lseg = t & 3;
        int o = o0 + pp * 64 + o_loc;
        float bo = bias[o];
        unsigned int esw = (unsigned)(o_loc & 7) << 4;
        size_t off = ((size_t)b * H_ + o) * L_ + l0 + lseg * 32;
        const float* xr = x + off;
        float* orow = out + off;
        #pragma unroll
        for (int j = 0; j < 8; ++j) {
            float4 e = *(const float4*)((char*)Eb + o_loc * 528 +
                                        (((unsigned)(lseg * 128 + j * 16)) ^ esw));
            float4 xv = *(const float4*)(xr + j * 4);
            float4 ov;
            ov.x = xv.x + bo + e.x;
            ov.y = xv.y + bo + e.y;
            ov.z = xv.z + bo + e.z;
            ov.w = xv.w + bo + e.w;
            *(float4*)(orow + j * 4) = ov;
        }
        __syncthreads();
    }
}

// ---------------------------------------------------------------------------
extern "C" void kernel_launch(void* const* d_in, const int* in_sizes, int n_in,
                              void* d_out, int out_size, void* d_ws, size_t ws_size,
                              hipStream_t stream) {
    const float* x      = (const float*)d_in[0];
    const float* log_dt = (const float*)d_in[1];
    const float* A_re   = (const float*)d_in[2];
    const float* A_im   = (const float*)d_in[3];
    const float* C_re   = (const float*)d_in[4];
    const float* C_im   = (const float*)d_in[5];
    const float* D      = (const float*)d_in[6];
    const float* lnw    = (const float*)d_in[7];
    const float* lnb    = (const float*)d_in[8];
    const float* W      = (const float*)d_in[9];
    const float* bout   = (const float*)d_in[10];
    float* out = (float*)d_out;

    unsigned short* zb   = (unsigned short*)d_ws;           // BHL bf16
    unsigned short* gb   = zb + (size_t)BHL;                // BHL bf16
    unsigned short* gT   = gb + (size_t)BHL;                // BHL bf16
    unsigned short* mats = gT + (size_t)BHL;                // 512*20480 bf16
    float2* Wc = (float2*)(mats + 512 * (size_t)MATS_PER);  // 512*64 cplx
    unsigned short* Wbf = (unsigned short*)(Wc + 512 * 64); // 65536 bf16

    mats_kernel<<<512, 64, 0, stream>>>(log_dt, A_re, A_im, C_re, C_im, mats, Wc);
    wbf_kernel<<<64, 256, 0, stream>>>(W, Wbf);
    ln_kernel<<<dim3(L_ / 256, B_), 256, 0, stream>>>(x, lnw, lnb, zb);
    ssm_kernel<<<B_ * H_, 256, 0, stream>>>(zb, mats, Wc, D, gb);
    gt_kernel<<<dim3(L_ / 64, B_), 256, 0, stream>>>(gb, gT);
    outproj_kernel<<<dim3(L_ / 128, H_ / 128, B_), 256, 0, stream>>>(gT, Wbf, x, bout, out);
}

// Round 8
// 208.719 us; speedup vs baseline: 4.0508x; 1.0683x over previous
//
#include <hip/hip_runtime.h>
#include <math.h>

#define B_ 16
#define H_ 256
#define L_ 4096
#define N_ 64
#define HN (H_*N_)
#define HL (H_*L_)
#define BHL (B_*H_*L_)

#define WVT_OFS 0
#define TM_OFS  8192
#define E2T_OFS 12288
#define MATS_PER 20480

typedef short bf16x8 __attribute__((ext_vector_type(8)));
typedef float f32x4  __attribute__((ext_vector_type(4)));

__device__ __forceinline__ unsigned int pk2(float a, float b) {
    return ((__float_as_uint(a) + 0x8000u) >> 16) |
           ((__float_as_uint(b) + 0x8000u) & 0xffff0000u);
}
__device__ __forceinline__ unsigned short bfr(float a) {
    return (unsigned short)((__float_as_uint(a) + 0x8000u) >> 16);
}
__device__ __forceinline__ float ubf(unsigned short u) {
    return __uint_as_float(((unsigned int)u) << 16);
}

// ---------------------------------------------------------------------------
// Kernel 1: build per-(h,dir) matrices + w^64. 1 wave per (h,dir).
// ---------------------------------------------------------------------------
__global__ void __launch_bounds__(64) mats_kernel(const float* __restrict__ log_dt,
                                                  const float* __restrict__ A_re,
                                                  const float* __restrict__ A_im,
                                                  const float* __restrict__ C_re,
                                                  const float* __restrict__ C_im,
                                                  unsigned short* __restrict__ mats,
                                                  float2* __restrict__ Wc) {
    int hd = blockIdx.x;
    int h = hd >> 1, d = hd & 1;
    int m = threadIdx.x;
    __shared__ float2 pws[65 * 64];
    __shared__ float2 c2s[64];
    __shared__ float  Karr[64];

    int i = h * 64 + m;
    float dt = expf(log_dt[h]);
    float Are = A_re[i], Aim = A_im[i];
    float dr = dt * Are, di = dt * Aim;
    float er = expf(dr);
    float wr = er * cosf(di), wi = er * sinf(di);
    float em1r = wr - 1.0f, em1i = wi;
    float inv = 1.0f / (Are * Are + Aim * Aim);
    float qr = (em1r * Are + em1i * Aim) * inv;
    float qi = (em1i * Are - em1r * Aim) * inv;
    float Cr = C_re[d * HN + i], Ci = C_im[d * HN + i];
    float2 c2;
    c2.x = 2.0f * (Cr * qr - Ci * qi);
    c2.y = 2.0f * (Cr * qi + Ci * qr);
    c2s[m] = c2;
    float pr = 1.0f, pi = 0.0f;
    for (int k = 0; k < 64; ++k) {
        float2 p; p.x = pr; p.y = pi;
        pws[k * 64 + ((m + k) & 63)] = p;
        float t = pr * wr - pi * wi;
        pi = pr * wi + pi * wr;
        pr = t;
    }
    {
        float2 p; p.x = pr; p.y = pi;
        pws[64 * 64 + ((m + 64) & 63)] = p;
        Wc[hd * 64 + m] = p;
    }
    __syncthreads();
    {
        float kk = 0.f;
        for (int mm = 0; mm < 64; ++mm) {
            float2 c = c2s[mm];
            float2 pw = pws[m * 64 + ((mm + m) & 63)];
            kk += c.x * pw.x - c.y * pw.y;
        }
        Karr[m] = kk;
    }
    __syncthreads();
    unsigned short* mb = mats + (size_t)hd * MATS_PER;
    for (int i2 = 0; i2 < 32; ++i2) {
        int e0 = 2 * i2, e1 = e0 + 1;
        int k0 = d ? e0 : 63 - e0;
        int k1 = d ? e1 : 63 - e1;
        float2 p0 = pws[k0 * 64 + ((m + k0) & 63)];
        float2 p1 = pws[k1 * 64 + ((m + k1) & 63)];
        *(unsigned int*)(mb + WVT_OFS + (2 * m) * 64 + e0)     = pk2(p0.x, p1.x);
        *(unsigned int*)(mb + WVT_OFS + (2 * m + 1) * 64 + e0) = pk2(p0.y, p1.y);
    }
    for (int i2 = 0; i2 < 32; ++i2) {
        int e0 = 2 * i2, e1 = e0 + 1;
        float v0, v1;
        if (d == 0) {
            v0 = (e0 <= m) ? Karr[m - e0] : 0.f;
            v1 = (e1 <= m) ? Karr[m - e1] : 0.f;
        } else {
            v0 = (e0 > m) ? Karr[e0 - m - 1] : 0.f;
            v1 = (e1 > m) ? Karr[e1 - m - 1] : 0.f;
        }
        *(unsigned int*)(mb + TM_OFS + m * 64 + e0) = pk2(v0, v1);
    }
    {
        int kp = d ? (63 - m) : (m + 1);
        for (int mm = 0; mm < 64; ++mm) {
            float2 c = c2s[mm];
            float2 pw = pws[kp * 64 + ((mm + kp) & 63)];
            float vr = c.x * pw.x - c.y * pw.y;
            float vi = -(c.x * pw.y + c.y * pw.x);
            *(unsigned int*)(mb + E2T_OFS + m * 128 + 2 * mm) = pk2(vr, vi);
        }
    }
}

// ---------------------------------------------------------------------------
// Kernel 1b: W fp32 -> bf16
// ---------------------------------------------------------------------------
__global__ void __launch_bounds__(256) wbf_kernel(const float* __restrict__ W,
                                                  unsigned short* __restrict__ Wbf) {
    int i = (blockIdx.x * 256 + threadIdx.x) * 4;
    float4 v = *(const float4*)(W + i);
    uint2 u;
    u.x = pk2(v.x, v.y);
    u.y = pk2(v.z, v.w);
    *(uint2*)(Wbf + i) = u;
}

// ---------------------------------------------------------------------------
// Kernel 2: LayerNorm over channel dim H; writes z as bf16.
// ---------------------------------------------------------------------------
__global__ void __launch_bounds__(256) ln_kernel(const float* __restrict__ x,
                                                 const float* __restrict__ lnw,
                                                 const float* __restrict__ lnb,
                                                 unsigned short* __restrict__ zb) {
    int b  = blockIdx.y;
    int l0 = blockIdx.x * 256;
    int t  = threadIdx.x;
    int hq = t >> 6, lo = t & 63;
    int l  = l0 + lo * 4;
    __shared__ float4 r1[4][64];
    __shared__ float4 r2[4][64];
    __shared__ float4 muS[64];
    __shared__ float4 rsS[64];
    const float* xb = x + (size_t)b * HL;
    float4 s1 = {0.f,0.f,0.f,0.f}, s2 = {0.f,0.f,0.f,0.f};
    #pragma unroll 4
    for (int hh = 0; hh < 64; ++hh) {
        int h = hq * 64 + hh;
        float4 v = *(const float4*)(xb + (size_t)h * L_ + l);
        s1.x += v.x; s1.y += v.y; s1.z += v.z; s1.w += v.w;
        s2.x += v.x*v.x; s2.y += v.y*v.y; s2.z += v.z*v.z; s2.w += v.w*v.w;
    }
    r1[hq][lo] = s1; r2[hq][lo] = s2;
    __syncthreads();
    if (t < 64) {
        float4 S1 = r1[0][t], S2 = r2[0][t];
        #pragma unroll
        for (int q = 1; q < 4; ++q) {
            float4 a = r1[q][t], c = r2[q][t];
            S1.x += a.x; S1.y += a.y; S1.z += a.z; S1.w += a.w;
            S2.x += c.x; S2.y += c.y; S2.z += c.z; S2.w += c.w;
        }
        const float invH = 1.0f / 256.0f;
        float4 mu, rs;
        mu.x = S1.x*invH; mu.y = S1.y*invH; mu.z = S1.z*invH; mu.w = S1.w*invH;
        rs.x = rsqrtf(S2.x*invH - mu.x*mu.x + 1e-5f);
        rs.y = rsqrtf(S2.y*invH - mu.y*mu.y + 1e-5f);
        rs.z = rsqrtf(S2.z*invH - mu.z*mu.z + 1e-5f);
        rs.w = rsqrtf(S2.w*invH - mu.w*mu.w + 1e-5f);
        muS[t] = mu; rsS[t] = rs;
    }
    __syncthreads();
    float4 mu = muS[lo], rs = rsS[lo];
    #pragma unroll 4
    for (int hh = 0; hh < 64; ++hh) {
        int h = hq * 64 + hh;
        float w = lnw[h], bb = lnb[h];
        float4 v = *(const float4*)(xb + (size_t)h * L_ + l);
        float4 zz;
        zz.x = (v.x - mu.x) * rs.x * w + bb;
        zz.y = (v.y - mu.y) * rs.y * w + bb;
        zz.z = (v.z - mu.z) * rs.z * w + bb;
        zz.w = (v.w - mu.w) * rs.w * w + bb;
        uint2 u;
        u.x = pk2(zz.x, zz.y);
        u.y = pk2(zz.z, zz.w);
        *(uint2*)(zb + (size_t)b * HL + (size_t)h * L_ + l) = u;
    }
}

// ---------------------------------------------------------------------------
// Kernel 3: MFMA chunked S4D (exact R6 body; launch_bounds 4 -> 3 to lift the
// unified VGPR+AGPR cap from 128 to ~170 and eliminate scratch spill).
// ---------------------------------------------------------------------------
#define MFMA16(a,b,c) __builtin_amdgcn_mfma_f32_16x16x32_bf16((a),(b),(c),0,0,0)
#define SU_BASE 8192
#define GST_BASE 32768

__global__ void __launch_bounds__(256, 3) ssm_kernel(const unsigned short* __restrict__ zb,
                                                     const unsigned short* __restrict__ mats,
                                                     const float2* __restrict__ Wc,
                                                     const float* __restrict__ D,
                                                     unsigned short* __restrict__ gb) {
    int bh = blockIdx.x;
    int h  = bh & (H_ - 1);
    int t  = threadIdx.x;
    int w  = t >> 6, l = t & 63;
    int d  = w >> 1, p = w & 1;

    __shared__ __align__(16) char smem[40960];

    const unsigned short* mb = mats + (size_t)(h * 2 + d) * MATS_PER;

    // ---- stage z via global_load_lds (linear LDS dest, swizzled source) ----
    {
        const char* zrow = (const char*)(zb + (size_t)bh * L_);
        #pragma unroll
        for (int k = 0; k < 2; ++k) {
            int row = w * 16 + k * 8 + (l >> 3);
            int chunk = (l & 7) ^ (row & 7);
            const char* src = zrow + row * 128 + chunk * 16;
            __builtin_amdgcn_global_load_lds(
                (const __attribute__((address_space(1))) unsigned int*)src,
                (__attribute__((address_space(3))) unsigned int*)(smem + w * 2048 + k * 1024),
                16, 0, 0);
        }
    }
    __syncthreads();

    // ---- load Z A-frags ----
    bf16x8 za[4][2];
    int arow = l & 15;
    int koff = (l >> 4) * 8;
    #pragma unroll
    for (int cb = 0; cb < 4; ++cb) {
        int row = cb * 16 + arow;
        unsigned int sw = (row & 7) << 4;
        #pragma unroll
        for (int kb = 0; kb < 2; ++kb) {
            unsigned int byte = (unsigned)(row * 128 + (kb * 32 + koff) * 2) ^ sw;
            za[cb][kb] = *(bf16x8*)(smem + byte);
        }
    }

    // ---- M1: U = Z * Wv ----
    char* sUd = smem + SU_BASE + d * 16384;
    #pragma unroll
    for (int mcb = 0; mcb < 4; ++mcb) {
        int mcblk = p * 4 + mcb;
        const unsigned short* wv = mb + WVT_OFS + (mcblk * 16 + arow) * 64 + koff;
        bf16x8 b0 = *(const bf16x8*)(wv);
        bf16x8 b1 = *(const bf16x8*)(wv + 32);
        #pragma unroll
        for (int cb = 0; cb < 4; ++cb) {
            f32x4 acc = {0.f, 0.f, 0.f, 0.f};
            acc = MFMA16(za[cb][0], b0, acc);
            acc = MFMA16(za[cb][1], b1, acc);
            int mc = mcblk * 16 + arow;
            #pragma unroll
            for (int rr = 0; rr < 4; ++rr) {
                int c = cb * 16 + (l >> 4) * 4 + rr;
                unsigned int byte = ((unsigned)(c * 256 + mc * 2)) ^ ((c & 7) << 4);
                *(unsigned short*)(sUd + byte) = bfr(acc[rr]);
            }
        }
    }
    __syncthreads();

    // ---- scan over 64 chunks (p==0 waves; lane = mode) ----
    if (p == 0) {
        float2 w64 = Wc[(h * 2 + d) * 64 + l];
        float sr = 0.f, si = 0.f;
        if (d == 0) {
            for (int c = 0; c < 64; ++c) {
                unsigned int byte = ((unsigned)(c * 256 + l * 4)) ^ ((c & 7) << 4);
                unsigned int uu = *(unsigned int*)(sUd + byte);
                float ur = __uint_as_float(uu << 16);
                float ui = __uint_as_float(uu & 0xffff0000u);
                *(unsigned int*)(sUd + byte) = pk2(sr, si);
                float nsr = fmaf(w64.x, sr, fmaf(-w64.y, si, ur));
                float nsi = fmaf(w64.x, si, fmaf(w64.y, sr, ui));
                sr = nsr; si = nsi;
            }
        } else {
            for (int c = 63; c >= 0; --c) {
                unsigned int byte = ((unsigned)(c * 256 + l * 4)) ^ ((c & 7) << 4);
                unsigned int uu = *(unsigned int*)(sUd + byte);
                float ur = __uint_as_float(uu << 16);
                float ui = __uint_as_float(uu & 0xffff0000u);
                *(unsigned int*)(sUd + byte) = pk2(sr, si);
                float nsr = fmaf(w64.x, sr, fmaf(-w64.y, si, ur));
                float nsi = fmaf(w64.x, si, fmaf(w64.y, sr, ui));
                sr = nsr; si = nsi;
            }
        }
    }
    __syncthreads();

    // ---- M2+M3: Y = Z*T^T + Sb*E2^T ----
    f32x4 yacc[2][4];
    #pragma unroll
    for (int jb = 0; jb < 2; ++jb) {
        int jblk = p * 2 + jb;
        const unsigned short* tm = mb + TM_OFS + (jblk * 16 + arow) * 64 + koff;
        bf16x8 tb0 = *(const bf16x8*)(tm);
        bf16x8 tb1 = *(const bf16x8*)(tm + 32);
        const unsigned short* et = mb + E2T_OFS + (jblk * 16 + arow) * 128 + koff;
        bf16x8 eb0 = *(const bf16x8*)(et);
        bf16x8 eb1 = *(const bf16x8*)(et + 32);
        bf16x8 eb2 = *(const bf16x8*)(et + 64);
        bf16x8 eb3 = *(const bf16x8*)(et + 96);
        #pragma unroll
        for (int cb = 0; cb < 4; ++cb) {
            f32x4 acc = {0.f, 0.f, 0.f, 0.f};
            acc = MFMA16(za[cb][0], tb0, acc);
            acc = MFMA16(za[cb][1], tb1, acc);
            int row = cb * 16 + arow;
            unsigned int sw = (row & 7) << 4;
            bf16x8 sa0 = *(bf16x8*)(sUd + (((unsigned)(row * 256 + (0 * 32 + koff) * 2)) ^ sw));
            bf16x8 sa1 = *(bf16x8*)(sUd + (((unsigned)(row * 256 + (1 * 32 + koff) * 2)) ^ sw));
            bf16x8 sa2 = *(bf16x8*)(sUd + (((unsigned)(row * 256 + (2 * 32 + koff) * 2)) ^ sw));
            bf16x8 sa3 = *(bf16x8*)(sUd + (((unsigned)(row * 256 + (3 * 32 + koff) * 2)) ^ sw));
            acc = MFMA16(sa0, eb0, acc);
            acc = MFMA16(sa1, eb1, acc);
            acc = MFMA16(sa2, eb2, acc);
            acc = MFMA16(sa3, eb3, acc);
            yacc[jb][cb] = acc;
        }
    }
    __syncthreads();

    // ---- exchange bwd Y; combine + GELU into gstage; coalesced store ----
    float* Yb = (float*)(smem + SU_BASE);
    if (d == 1) {
        #pragma unroll
        for (int jb = 0; jb < 2; ++jb) {
            int j = (p * 2 + jb) * 16 + arow;
            #pragma unroll
            for (int cb = 0; cb < 4; ++cb) {
                #pragma unroll
                for (int rr = 0; rr < 4; ++rr) {
                    int c = cb * 16 + (l >> 4) * 4 + rr;
                    Yb[c * 66 + j] = yacc[jb][cb][rr];
                }
            }
        }
    }
    __syncthreads();
    if (d == 0) {
        float dv = D[h];
        #pragma unroll
        for (int jb = 0; jb < 2; ++jb) {
            int j = (p * 2 + jb) * 16 + arow;
            #pragma unroll
            for (int cb = 0; cb < 4; ++cb) {
                #pragma unroll
                for (int rr = 0; rr < 4; ++rr) {
                    int c = cb * 16 + (l >> 4) * 4 + rr;
                    unsigned int zbyte = ((unsigned)(c * 128 + j * 2)) ^ ((c & 7) << 4);
                    float zv = ubf(*(unsigned short*)(smem + zbyte));
                    float y = yacc[jb][cb][rr] + Yb[c * 66 + j] + dv * zv;
                    float inner = 0.7978845608028654f * (y + 0.044715f * y * y * y);
                    float gv = 0.5f * y * (1.0f + tanhf(inner));
                    *(unsigned short*)(smem + GST_BASE + zbyte) = bfr(gv);
                }
            }
        }
    }
    __syncthreads();
    {
        int c2 = t >> 2, s2 = t & 3;
        unsigned int rsw = (c2 & 7) << 4;
        char* go = (char*)(gb + (size_t)bh * L_);
        uint4 a0 = *(const uint4*)(smem + GST_BASE + (((unsigned)(c2 * 128 + s2 * 32)) ^ rsw));
        uint4 a1 = *(const uint4*)(smem + GST_BASE + (((unsigned)(c2 * 128 + s2 * 32 + 16)) ^ rsw));
        *(uint4*)(go + c2 * 128 + s2 * 32)      = a0;
        *(uint4*)(go + c2 * 128 + s2 * 32 + 16) = a1;
    }
}

// ---------------------------------------------------------------------------
// Kernel 4: transpose g[b][h][l] bf16 -> gT[b][l][h] bf16 via LDS.
// ---------------------------------------------------------------------------
__global__ void __launch_bounds__(256, 4) gt_kernel(const unsigned short* __restrict__ gb,
                                                    unsigned short* __restrict__ gT) {
    int b  = blockIdx.y;
    int l0 = blockIdx.x * 64;
    int t  = threadIdx.x;
    __shared__ __align__(16) char lT[64 * 512];   // 32 KB: [l][h] bf16 rows 512 B
    const unsigned short* gp = gb + ((size_t)b * H_ + t) * L_ + l0;
    uint4 v[8];
    #pragma unroll
    for (int j8 = 0; j8 < 8; ++j8) v[j8] = *(const uint4*)(gp + j8 * 8);
    #pragma unroll
    for (int j8 = 0; j8 < 8; ++j8) {
        #pragma unroll
        for (int e = 0; e < 8; ++e) {
            int l = j8 * 8 + e;
            unsigned short val = ((const unsigned short*)&v[j8])[e];
            *(unsigned short*)(lT + (((unsigned)(l * 512 + t * 2)) ^ ((l & 7) << 4))) = val;
        }
    }
    __syncthreads();
    int l = t >> 2, seg = t & 3;
    unsigned short* dst = gT + ((size_t)b * L_ + l0 + l) * 256 + seg * 64;
    unsigned int sw = (l & 7) << 4;
    #pragma unroll
    for (int j = 0; j < 8; ++j) {
        uint4 u = *(const uint4*)(lT + (((unsigned)(l * 512 + seg * 128 + j * 16)) ^ sw));
        *(uint4*)(dst + j * 8) = u;
    }
}

// ---------------------------------------------------------------------------
// Kernel 5: out[b,o,l] = x + b_out[o] + sum_h W[o,h]*g[b,h,l], bf16 MFMA.
// ---------------------------------------------------------------------------
__global__ void __launch_bounds__(256, 3) outproj_kernel(
        const unsigned short* __restrict__ gT,
        const unsigned short* __restrict__ Wbf,
        const float* __restrict__ x,
        const float* __restrict__ bias,
        float* __restrict__ out) {
    int b  = blockIdx.z;
    int o0 = blockIdx.y * 128;
    int l0 = blockIdx.x * 128;
    int t  = threadIdx.x;
    int w  = t >> 6, lane = t & 63;
    int wr = w >> 1, wc = w & 1;
    int l15 = lane & 15, q = lane >> 4;

    __shared__ __align__(16) char lds[34816];
    unsigned short* At = (unsigned short*)lds;
    unsigned short* Bt = (unsigned short*)(lds + 16384);

    f32x4 acc[4][4];
    #pragma unroll
    for (int i = 0; i < 4; ++i)
        #pragma unroll
        for (int j = 0; j < 4; ++j) acc[i][j] = (f32x4){0.f, 0.f, 0.f, 0.f};

    const unsigned short* gTb = gT + ((size_t)b * L_ + l0) * 256;
    const unsigned short* Wb0 = Wbf + (size_t)o0 * 256;
    unsigned int swz = (unsigned)(l15 & 7) << 4;

    for (int kt = 0; kt < 4; ++kt) {
        int k0 = kt * 64;
        #pragma unroll
        for (int s = 0; s < 4; ++s) {
            int id = (w * 4 + s) * 64 + lane;
            int row = id >> 3, ch = id & 7;
            int chl = ch ^ (row & 7);
            uint4 va = *(const uint4*)(gTb + (size_t)row * 256 + k0 + chl * 8);
            uint4 vb = *(const uint4*)(Wb0 + (size_t)row * 256 + k0 + chl * 8);
            *(uint4*)(At + id * 8) = va;
            *(uint4*)(Bt + id * 8) = vb;
        }
        __syncthreads();
        #pragma unroll
        for (int kk = 0; kk < 2; ++kk) {
            bf16x8 af[4], bfr_[4];
            #pragma unroll
            for (int rb = 0; rb < 4; ++rb) {
                int li = wr * 64 + rb * 16 + l15;
                af[rb] = *(const bf16x8*)((char*)At + li * 128 + (((kk * 64 + q * 16)) ^ swz));
                int oi = wc * 64 + rb * 16 + l15;
                bfr_[rb] = *(const bf16x8*)((char*)Bt + oi * 128 + (((kk * 64 + q * 16)) ^ swz));
            }
            #pragma unroll
            for (int rb = 0; rb < 4; ++rb)
                #pragma unroll
                for (int cb = 0; cb < 4; ++cb)
                    acc[rb][cb] = MFMA16(af[rb], bfr_[cb], acc[rb][cb]);
        }
        __syncthreads();
    }

    float* Eb = (float*)lds;
    for (int pp = 0; pp < 2; ++pp) {
        if (wc == pp) {
            #pragma unroll
            for (int cb = 0; cb < 4; ++cb) {
                int o_loc = cb * 16 + l15;
                unsigned int esw = (unsigned)(o_loc & 7) << 4;
                #pragma unroll
                for (int rb = 0; rb < 4; ++rb) {
                    int colbase = wr * 64 + rb * 16 + q * 4;
                    #pragma unroll
                    for (int r = 0; r < 4; ++r) {
                        int col = colbase + r;
                        *(float*)((char*)Eb + o_loc * 528 + (((unsigned)(col * 4)) ^ esw)) =
                            acc[rb][cb][r];
                    }
                }
            }
        }
        __syncthreads();
        int o_loc = t >> 2, lseg = t & 3;
        int o = o0 + pp * 64 + o_loc;
        float bo = bias[o];
        unsigned int esw = (unsigned)(o_loc & 7) << 4;
        size_t off = ((size_t)b * H_ + o) * L_ + l0 + lseg * 32;
        const float* xr = x + off;
        float* orow = out + off;
        #pragma unroll
        for (int j = 0; j < 8; ++j) {
            float4 e = *(const float4*)((char*)Eb + o_loc * 528 +
                                        (((unsigned)(lseg * 128 + j * 16)) ^ esw));
            float4 xv = *(const float4*)(xr + j * 4);
            float4 ov;
            ov.x = xv.x + bo + e.x;
            ov.y = xv.y + bo + e.y;
            ov.z = xv.z + bo + e.z;
            ov.w = xv.w + bo + e.w;
            *(float4*)(orow + j * 4) = ov;
        }
        __syncthreads();
    }
}

// ---------------------------------------------------------------------------
extern "C" void kernel_launch(void* const* d_in, const int* in_sizes, int n_in,
                              void* d_out, int out_size, void* d_ws, size_t ws_size,
                              hipStream_t stream) {
    const float* x      = (const float*)d_in[0];
    const float* log_dt = (const float*)d_in[1];
    const float* A_re   = (const float*)d_in[2];
    const float* A_im   = (const float*)d_in[3];
    const float* C_re   = (const float*)d_in[4];
    const float* C_im   = (const float*)d_in[5];
    const float* D      = (const float*)d_in[6];
    const float* lnw    = (const float*)d_in[7];
    const float* lnb    = (const float*)d_in[8];
    const float* W      = (const float*)d_in[9];
    const float* bout   = (const float*)d_in[10];
    float* out = (float*)d_out;

    unsigned short* zb   = (unsigned short*)d_ws;           // BHL bf16
    unsigned short* gb   = zb + (size_t)BHL;                // BHL bf16
    unsigned short* gT   = gb + (size_t)BHL;                // BHL bf16
    unsigned short* mats = gT + (size_t)BHL;                // 512*20480 bf16
    float2* Wc = (float2*)(mats + 512 * (size_t)MATS_PER);  // 512*64 cplx
    unsigned short* Wbf = (unsigned short*)(Wc + 512 * 64); // 65536 bf16

    mats_kernel<<<512, 64, 0, stream>>>(log_dt, A_re, A_im, C_re, C_im, mats, Wc);
    wbf_kernel<<<64, 256, 0, stream>>>(W, Wbf);
    ln_kernel<<<dim3(L_ / 256, B_), 256, 0, stream>>>(x, lnw, lnb, zb);
    ssm_kernel<<<B_ * H_, 256, 0, stream>>>(zb, mats, Wc, D, gb);
    gt_kernel<<<dim3(L_ / 64, B_), 256, 0, stream>>>(gb, gT);
    outproj_kernel<<<dim3(L_ / 128, H_ / 128, B_), 256, 0, stream>>>(gT, Wbf, x, bout, out);
}